// Round 10
// baseline (8867.989 us; speedup 1.0000x reference)
//
#include <hip/hip_runtime.h>
#include <hip/hip_bf16.h>

#define S_LEN   512
#define BATCH   64
#define DH      512
#define KDIM    1024      // 2*DH (concat [h, x])
#define NCOLS   64        // 4 gates * 16 hidden units per WG
#define WGL     32        // WGs per layer
#define NWG     64
#define THREADS 256
#define LDS_BYTES (NCOLS * KDIM * 2)   // 131072 B weights per WG
#define FLAG_STRIDE 32                 // uints: one flag per 128-B line

typedef __attribute__((ext_vector_type(8))) unsigned short u16x8;
typedef __attribute__((ext_vector_type(8))) __bf16         bf16x8;
typedef __attribute__((ext_vector_type(4))) float          f32x4;
typedef __attribute__((ext_vector_type(4))) unsigned       u32x4;

__device__ __forceinline__ unsigned short f2bf(float f) {
    unsigned u = __float_as_uint(f);
    return (unsigned short)((u + 0x7fffu + ((u >> 16) & 1u)) >> 16);   // RNE
}
__device__ __forceinline__ float sigmoid_f(float x) { return 1.f / (1.f + __expf(-x)); }
__device__ __forceinline__ float tanh_f(float x) {
    float e = __expf(2.f * x);
    return 1.f - 2.f / (e + 1.f);
}
__device__ __forceinline__ f32x4 mfma16(bf16x8 a, bf16x8 b, f32x4 c) {
    return __builtin_amdgcn_mfma_f32_16x16x32_bf16(a, b, c, 0, 0, 0);
}
// 32-bit agent-scope relaxed atomics (proven instruction class, compiler-tracked).
__device__ __forceinline__ unsigned ld_coh32(const unsigned* p) {
    return __hip_atomic_load(p, __ATOMIC_RELAXED, __HIP_MEMORY_SCOPE_AGENT);
}
__device__ __forceinline__ void st_coh32(unsigned* p, unsigned v) {
    __hip_atomic_store(p, v, __ATOMIC_RELAXED, __HIP_MEMORY_SCOPE_AGENT);
}

// ws layout:
//   ushort[0]      : h0buf [2][64][512]  bf16    layer0 h ping-pong
//   ushort[65536]  : hx1buf[2][64][1024] bf16    layer1 [h,x] ping-pong
//   byte 393216    : flags[64 * 32] uint         per-WG flag, one per 128-B line
//   byte 401408    : epoch[64 * 32] uint         per-WG PRIVATE epoch copy
#define WS_H0    0
#define WS_HX1   (2 * BATCH * DH)
#define WS_BAR_B 393216
#define WS_EPO_B 401408

__global__ void lstm_init(const float* __restrict__ seq,
                          const float* __restrict__ h_init,
                          unsigned short* __restrict__ ws) {
    int i = blockIdx.x * blockDim.x + threadIdx.x;   // 0 .. 32767
    unsigned* flags = (unsigned*)((char*)ws + WS_BAR_B);
    unsigned* epoch = (unsigned*)((char*)ws + WS_EPO_B);
    if (i < NWG) { flags[i * FLAG_STRIDE] = 0; epoch[i * FLAG_STRIDE] = 0; }
    if (i < BATCH * DH) {
        int row = i >> 9;
        int col = i & 511;
        ws[WS_H0 + row * DH + col] = f2bf(h_init[i]);                    // h0 par0
        ws[WS_HX1 + BATCH * KDIM + row * KDIM + col] =                   // hx1 par1 h-part
            f2bf(h_init[(size_t)BATCH * DH + i]);
    }
}

__global__ __launch_bounds__(THREADS, 1)
void lstm_main(const float* __restrict__ seq,
               const float* __restrict__ Wf, const float* __restrict__ Bf,
               const float* __restrict__ Wi, const float* __restrict__ Bi,
               const float* __restrict__ Wc, const float* __restrict__ Bc,
               const float* __restrict__ Wo, const float* __restrict__ Bo,
               float* __restrict__ out, unsigned short* __restrict__ ws)
{
    extern __shared__ unsigned short wlds[];   // [NCOLS][KDIM] bf16, XOR-swizzled

    const int wg    = blockIdx.x;
    const int layer = (wg >= WGL) ? 1 : 0;
    const int wid   = layer ? wg - WGL : wg;
    const int jbase = wid * 16;
    const int tid   = threadIdx.x;
    const int lane  = tid & 63;
    const int wave  = tid >> 6;

    unsigned short* h0b  = ws + WS_H0;
    unsigned short* hx1b = ws + WS_HX1;
    unsigned* flags = (unsigned*)((char*)ws + WS_BAR_B);
    unsigned* epoch = (unsigned*)((char*)ws + WS_EPO_B);

    // ---- stage this WG's weight slice into LDS (bf16, swizzled), once ----
    {
        const size_t woff = (size_t)layer * KDIM * DH;
        const float* Wg[4] = { Wf + woff, Wi + woff, Wc + woff, Wo + woff };
        for (int idx = tid; idx < NCOLS * KDIM; idx += THREADS) {
            int mcol = idx & (NCOLS - 1);          // gate*16 + unit
            int k    = idx >> 6;
            float w  = Wg[mcol >> 4][(size_t)k * DH + jbase + (mcol & 15)];
            unsigned byte = ((unsigned)mcol * 2048u + (unsigned)k * 2u)
                          ^ (((unsigned)mcol & 7u) << 4);
            wlds[byte >> 1] = f2bf(w);
        }
    }

    // ---- transposed-MFMA geometry: A=weights (rows=16 units), B=acts (cols=16 batch)
    // D mapping (m89): col = lane&15 -> batch, row = (lane>>4)*4 + r -> unit.
    const int ln  = lane & 15;
    const int lq  = lane >> 4;
    const int b   = wave * 16 + ln;          // this lane's batch row
    const int jq  = jbase + (lq << 2);       // first of 4 consecutive unit cols
    const int klo = lq * 8;                  // k offset within each K=32 chunk
    const unsigned sw  = ((unsigned)(lane & 7)) << 4;
    const unsigned wbF = (0u * 16 + (unsigned)ln) * 2048u;
    const unsigned wbI = (1u * 16 + (unsigned)ln) * 2048u;
    const unsigned wbC = (2u * 16 + (unsigned)ln) * 2048u;
    const unsigned wbO = (3u * 16 + (unsigned)ln) * 2048u;

    float bFa[4], bIa[4], bCa[4], bOa[4];
    #pragma unroll
    for (int r = 0; r < 4; ++r) {
        bFa[r] = Bf[layer * DH + jq + r];
        bIa[r] = Bi[layer * DH + jq + r];
        bCa[r] = Bc[layer * DH + jq + r];
        bOa[r] = Bo[layer * DH + jq + r];
    }
    __syncthreads();

    float cs[4] = {0.f, 0.f, 0.f, 0.f};

    for (int it = 0; it <= S_LEN; ++it) {
        const bool active = layer ? (it >= 1) : (it < S_LEN);
        const int  t      = layer ? it - 1 : it;

        if (active) {
            const int par = it & 1;
            f32x4 eF = {0,0,0,0}, eI = {0,0,0,0}, eC = {0,0,0,0}, eO = {0,0,0,0};
            f32x4 oF = {0,0,0,0}, oI = {0,0,0,0}, oC = {0,0,0,0}, oO = {0,0,0,0};

            #define CONS(s_, av_) do {                                                 \
                const unsigned kb = ((unsigned)(s_) * 64u + (unsigned)klo * 2u) ^ sw;  \
                bf16x8 wF = __builtin_bit_cast(bf16x8, *(const u16x8*)((const char*)wlds + wbF + kb)); \
                bf16x8 wI = __builtin_bit_cast(bf16x8, *(const u16x8*)((const char*)wlds + wbI + kb)); \
                bf16x8 wC = __builtin_bit_cast(bf16x8, *(const u16x8*)((const char*)wlds + wbC + kb)); \
                bf16x8 wO = __builtin_bit_cast(bf16x8, *(const u16x8*)((const char*)wlds + wbO + kb)); \
                if ((s_) & 1) {                                                        \
                    oF = mfma16(wF, (av_), oF); oI = mfma16(wI, (av_), oI);            \
                    oC = mfma16(wC, (av_), oC); oO = mfma16(wO, (av_), oO);            \
                } else {                                                               \
                    eF = mfma16(wF, (av_), eF); eI = mfma16(wI, (av_), eI);            \
                    eC = mfma16(wC, (av_), eC); eO = mfma16(wO, (av_), eO);            \
                } } while (0)
            #define CONS_Q(s_, arr_, base_) do {                                       \
                u32x4 q_ = { (arr_)[(base_)], (arr_)[(base_)+1],                       \
                             (arr_)[(base_)+2], (arr_)[(base_)+3] };                   \
                bf16x8 av_ = __builtin_bit_cast(bf16x8, q_);                           \
                CONS(s_, av_); } while (0)

            if (layer) {
                const unsigned* hp = (const unsigned*)
                    (hx1b + par * BATCH * KDIM + b * KDIM + klo);
                unsigned ahA[64], ahB[32], ahC[32];
                #pragma unroll
                for (int s = 0; s < 16; ++s)
                    #pragma unroll
                    for (int d = 0; d < 4; ++d)
                        ahA[s * 4 + d] = ld_coh32(hp + s * 16 + d);
                #pragma unroll
                for (int s = 16; s < 24; ++s)
                    #pragma unroll
                    for (int d = 0; d < 4; ++d)
                        ahB[(s - 16) * 4 + d] = ld_coh32(hp + s * 16 + d);
                #pragma unroll
                for (int s = 0; s < 16; ++s) CONS_Q(s, ahA, s * 4);
                #pragma unroll
                for (int s = 24; s < 32; ++s)
                    #pragma unroll
                    for (int d = 0; d < 4; ++d)
                        ahC[(s - 24) * 4 + d] = ld_coh32(hp + s * 16 + d);
                #pragma unroll
                for (int s = 16; s < 24; ++s) CONS_Q(s, ahB, (s - 16) * 4);
                #pragma unroll
                for (int s = 24; s < 32; ++s) CONS_Q(s, ahC, (s - 24) * 4);
            } else {
                const unsigned* hp = (const unsigned*)
                    (h0b + par * BATCH * DH + b * DH + klo);
                unsigned ahA[64];
                #pragma unroll
                for (int s = 0; s < 16; ++s)
                    #pragma unroll
                    for (int d = 0; d < 4; ++d)
                        ahA[s * 4 + d] = ld_coh32(hp + s * 16 + d);
                // consume x-part from seq (normal cached loads) while h flies
                const float* sp = seq + ((size_t)t * BATCH + b) * DH + klo;
                #pragma unroll
                for (int s = 16; s < 32; ++s) {
                    float4 v0 = *(const float4*)(sp + (s - 16) * 32);
                    float4 v1 = *(const float4*)(sp + (s - 16) * 32 + 4);
                    u16x8 tv;
                    tv[0]=f2bf(v0.x); tv[1]=f2bf(v0.y); tv[2]=f2bf(v0.z); tv[3]=f2bf(v0.w);
                    tv[4]=f2bf(v1.x); tv[5]=f2bf(v1.y); tv[6]=f2bf(v1.z); tv[7]=f2bf(v1.w);
                    bf16x8 av = __builtin_bit_cast(bf16x8, tv);
                    CONS(s, av);
                }
                #pragma unroll
                for (int s = 0; s < 16; ++s) CONS_Q(s, ahA, s * 4);
            }
            #undef CONS_Q
            #undef CONS

            float hv[4];
            #pragma unroll
            for (int r = 0; r < 4; ++r) {
                float fg = sigmoid_f(eF[r] + oF[r] + bFa[r]);
                float ig = sigmoid_f(eI[r] + oI[r] + bIa[r]);
                float ct = tanh_f  (eC[r] + oC[r] + bCa[r]);
                float og = sigmoid_f(eO[r] + oO[r] + bOa[r]);
                float cn = fg * cs[r] + ig * ct;
                cs[r] = cn;
                hv[r]  = og * tanh_f(cn);
            }
            const unsigned d0 = (unsigned)f2bf(hv[0]) | ((unsigned)f2bf(hv[1]) << 16);
            const unsigned d1 = (unsigned)f2bf(hv[2]) | ((unsigned)f2bf(hv[3]) << 16);
            const int npar = (it + 1) & 1;
            if (!layer) {
                unsigned* p0 = (unsigned*)(h0b + npar * BATCH * DH + b * DH + jq);
                st_coh32(p0, d0); st_coh32(p0 + 1, d1);
                unsigned* p1 = (unsigned*)(hx1b + npar * BATCH * KDIM + b * KDIM + DH + jq);
                st_coh32(p1, d0); st_coh32(p1 + 1, d1);
                if (t == S_LEN - 1) {
                    float* po = out + (size_t)S_LEN * BATCH * DH + (size_t)b * DH + jq;
                    #pragma unroll
                    for (int r = 0; r < 4; ++r) __builtin_nontemporal_store(hv[r], po + r);
                }
            } else {
                unsigned* p1 = (unsigned*)(hx1b + npar * BATCH * KDIM + b * KDIM + jq);
                st_coh32(p1, d0); st_coh32(p1 + 1, d1);
                float* po = out + ((size_t)t * BATCH + b) * DH + jq;
                #pragma unroll
                for (int r = 0; r < 4; ++r) __builtin_nontemporal_store(hv[r], po + r);
                if (t == S_LEN - 1) {
                    float* pl = out + (size_t)S_LEN * BATCH * DH + (size_t)BATCH * DH
                                    + (size_t)b * DH + jq;
                    #pragma unroll
                    for (int r = 0; r < 4; ++r) __builtin_nontemporal_store(hv[r], pl + r);
                }
            }
        }

        // ---- hierarchical flag barrier (r8 semantics, 64x less poll traffic) ----
        // Publish: unchanged (syncthreads drains vmcnt -> tid0 flag store).
        // Detect: ONLY WG0's wave0 polls the 64 flags (lane w -> flags[w], one
        // load instruction per round). On success each lane stores the epoch to
        // WG w's PRIVATE padded line (one wave-parallel store). Every WG then
        // spins on its own line only (uniform address -> 1 coalesced request),
        // eliminating the 4096-lane poll storm on shared lines that was
        // saturating the coherence fabric and inflating all cross-XCD latency.
        if (it < S_LEN) {
            const unsigned need = (unsigned)(it + 1);
            __syncthreads();
            if (tid == 0)
                st_coh32(&flags[wg * FLAG_STRIDE], need);
            if (wg == 0 && wave == 0) {
                unsigned v = ld_coh32(&flags[lane * FLAG_STRIDE]);
                while (!__all((int)(v >= need))) {
                    __builtin_amdgcn_s_sleep(1);
                    v = ld_coh32(&flags[lane * FLAG_STRIDE]);
                }
                st_coh32(&epoch[lane * FLAG_STRIDE], need);   // fan-out, 1 store op
            }
            if (wave == 0) {
                unsigned v = ld_coh32(&epoch[wg * FLAG_STRIDE]);
                while (v < need) {
                    __builtin_amdgcn_s_sleep(1);
                    v = ld_coh32(&epoch[wg * FLAG_STRIDE]);
                }
            }
            __syncthreads();
            __builtin_amdgcn_sched_barrier(0);
        }
    }
}

extern "C" void kernel_launch(void* const* d_in, const int* in_sizes, int n_in,
                              void* d_out, int out_size, void* d_ws, size_t ws_size,
                              hipStream_t stream) {
    const float* seq    = (const float*)d_in[0];
    const float* h_init = (const float*)d_in[1];
    const float* Wf     = (const float*)d_in[2];
    const float* Bf     = (const float*)d_in[3];
    const float* Wi     = (const float*)d_in[4];
    const float* Bi     = (const float*)d_in[5];
    const float* Wc     = (const float*)d_in[6];
    const float* Bc     = (const float*)d_in[7];
    const float* Wo     = (const float*)d_in[8];
    const float* Bo     = (const float*)d_in[9];
    float* out          = (float*)d_out;
    unsigned short* ws  = (unsigned short*)d_ws;

    hipFuncSetAttribute((const void*)lstm_main,
                        hipFuncAttributeMaxDynamicSharedMemorySize, LDS_BYTES);

    hipLaunchKernelGGL(lstm_init, dim3(128), dim3(THREADS), 0, stream, seq, h_init, ws);

    void* args[] = { (void*)&seq,
                     (void*)&Wf, (void*)&Bf,
                     (void*)&Wi, (void*)&Bi,
                     (void*)&Wc, (void*)&Bc,
                     (void*)&Wo, (void*)&Bo,
                     (void*)&out, (void*)&ws };
    hipLaunchCooperativeKernel((void*)lstm_main, dim3(NWG), dim3(THREADS),
                               args, LDS_BYTES, stream);
}

// Round 11
// 8664.317 us; speedup vs baseline: 1.0235x; 1.0235x over previous
//
#include <hip/hip_runtime.h>
#include <hip/hip_bf16.h>

#define S_LEN   512
#define BATCH   64
#define DH      512
#define KDIM    1024      // 2*DH (concat [h, x])
#define NCOLS   64        // 4 gates * 16 hidden units per WG
#define WGL     32        // WGs per layer
#define NWG     64
#define THREADS 256
#define LDS_BYTES (NCOLS * KDIM * 2)   // 131072 B weights per WG
#define FLAG_STRIDE 32                 // uints: one flag per 128-B line
#define NSLOT   4                      // rotation depth (gives 2-step WAR slack)

typedef __attribute__((ext_vector_type(8))) unsigned short u16x8;
typedef __attribute__((ext_vector_type(8))) __bf16         bf16x8;
typedef __attribute__((ext_vector_type(4))) float          f32x4;
typedef __attribute__((ext_vector_type(4))) unsigned       u32x4;

__device__ __forceinline__ unsigned short f2bf(float f) {
    unsigned u = __float_as_uint(f);
    return (unsigned short)((u + 0x7fffu + ((u >> 16) & 1u)) >> 16);   // RNE
}
__device__ __forceinline__ float sigmoid_f(float x) { return 1.f / (1.f + __expf(-x)); }
__device__ __forceinline__ float tanh_f(float x) {
    float e = __expf(2.f * x);
    return 1.f - 2.f / (e + 1.f);
}
__device__ __forceinline__ f32x4 mfma16(bf16x8 a, bf16x8 b, f32x4 c) {
    return __builtin_amdgcn_mfma_f32_16x16x32_bf16(a, b, c, 0, 0, 0);
}
// 32-bit agent-scope relaxed atomics (proven instruction class, compiler-tracked).
__device__ __forceinline__ unsigned ld_coh32(const unsigned* p) {
    return __hip_atomic_load(p, __ATOMIC_RELAXED, __HIP_MEMORY_SCOPE_AGENT);
}
__device__ __forceinline__ void st_coh32(unsigned* p, unsigned v) {
    __hip_atomic_store(p, v, __ATOMIC_RELAXED, __HIP_MEMORY_SCOPE_AGENT);
}

// ws layout:
//   ushort[0]      : h0buf [4][64][512]  bf16   (256 KB) layer0 h rotation
//   ushort[131072] : hx1buf[4][64][1024] bf16   (512 KB) layer1 [h,x] rotation
//   byte 786432    : flags[64 * 32] uint        per-WG flag, one per 128-B line
#define WS_H0    0
#define WS_HX1   (NSLOT * BATCH * DH)            // 131072 ushorts
#define WS_BAR_B 786432

__global__ void lstm_init(const float* __restrict__ seq,
                          const float* __restrict__ h_init,
                          unsigned short* __restrict__ ws) {
    int i = blockIdx.x * blockDim.x + threadIdx.x;   // 0 .. 32767
    unsigned* flags = (unsigned*)((char*)ws + WS_BAR_B);
    if (i < NWG) flags[i * FLAG_STRIDE] = 0;         // re-zeroed every launch
    if (i < BATCH * DH) {
        int row = i >> 9;
        int col = i & 511;
        // h0 slot 0 <- h_init[layer0]   (read by L0 at it=0)
        ws[WS_H0 + i] = f2bf(h_init[i]);
        // hx1 slot 1 h-part <- h_init[layer1]   (read by L1 at it=1)
        ws[WS_HX1 + 1 * BATCH * KDIM + row * KDIM + col] =
            f2bf(h_init[(size_t)BATCH * DH + i]);
    }
}

__global__ __launch_bounds__(THREADS, 1)
void lstm_main(const float* __restrict__ seq,
               const float* __restrict__ Wf, const float* __restrict__ Bf,
               const float* __restrict__ Wi, const float* __restrict__ Bi,
               const float* __restrict__ Wc, const float* __restrict__ Bc,
               const float* __restrict__ Wo, const float* __restrict__ Bo,
               float* __restrict__ out, unsigned short* __restrict__ ws)
{
    extern __shared__ unsigned short wlds[];   // [NCOLS][KDIM] bf16, XOR-swizzled

    const int wg    = blockIdx.x;
    const int layer = (wg >= WGL) ? 1 : 0;
    const int wid   = layer ? wg - WGL : wg;
    const int jbase = wid * 16;
    const int tid   = threadIdx.x;
    const int lane  = tid & 63;
    const int wave  = tid >> 6;

    unsigned short* h0b  = ws + WS_H0;
    unsigned short* hx1b = ws + WS_HX1;
    unsigned* flags = (unsigned*)((char*)ws + WS_BAR_B);

    // ---- stage this WG's weight slice into LDS (bf16, swizzled), once ----
    {
        const size_t woff = (size_t)layer * KDIM * DH;
        const float* Wg[4] = { Wf + woff, Wi + woff, Wc + woff, Wo + woff };
        for (int idx = tid; idx < NCOLS * KDIM; idx += THREADS) {
            int mcol = idx & (NCOLS - 1);          // gate*16 + unit
            int k    = idx >> 6;
            float w  = Wg[mcol >> 4][(size_t)k * DH + jbase + (mcol & 15)];
            unsigned byte = ((unsigned)mcol * 2048u + (unsigned)k * 2u)
                          ^ (((unsigned)mcol & 7u) << 4);
            wlds[byte >> 1] = f2bf(w);
        }
    }

    // ---- transposed-MFMA geometry: A=weights (rows=16 units), B=acts (cols=16 batch)
    // D mapping (m89): col = lane&15 -> batch, row = (lane>>4)*4 + r -> unit.
    const int ln  = lane & 15;
    const int lq  = lane >> 4;
    const int b   = wave * 16 + ln;          // this lane's batch row
    const int jq  = jbase + (lq << 2);       // first of 4 consecutive unit cols
    const int klo = lq * 8;                  // k offset within each K=32 chunk
    const unsigned sw  = ((unsigned)(lane & 7)) << 4;
    const unsigned wbF = (0u * 16 + (unsigned)ln) * 2048u;
    const unsigned wbI = (1u * 16 + (unsigned)ln) * 2048u;
    const unsigned wbC = (2u * 16 + (unsigned)ln) * 2048u;
    const unsigned wbO = (3u * 16 + (unsigned)ln) * 2048u;

    float bFa[4], bIa[4], bCa[4], bOa[4];
    #pragma unroll
    for (int r = 0; r < 4; ++r) {
        bFa[r] = Bf[layer * DH + jq + r];
        bIa[r] = Bi[layer * DH + jq + r];
        bCa[r] = Bc[layer * DH + jq + r];
        bOa[r] = Bo[layer * DH + jq + r];
    }
    // poll partition: lanes 0-31 watch own-layer flags (need it+1);
    // lanes 32-63 watch the other layer's flags (L1 needs L0>=it+1 data dep;
    // L0 needs L1>=it-1 WAR slack from the 4-slot rotation).
    const int pidx = (lane < 32) ? (layer * WGL + lane)
                                 : ((1 - layer) * WGL + (lane - 32));
    const unsigned* pflag = &flags[pidx * FLAG_STRIDE];
    __syncthreads();

    float cs[4] = {0.f, 0.f, 0.f, 0.f};

    for (int it = 0; it <= S_LEN; ++it) {
        const bool active = layer ? (it >= 1) : (it < S_LEN);
        const int  t      = layer ? it - 1 : it;
        float hv[4];

        if (active) {
            const int par = it & (NSLOT - 1);
            f32x4 eF = {0,0,0,0}, eI = {0,0,0,0}, eC = {0,0,0,0}, eO = {0,0,0,0};
            f32x4 oF = {0,0,0,0}, oI = {0,0,0,0}, oC = {0,0,0,0}, oO = {0,0,0,0};

            #define CONS(s_, av_) do {                                                 \
                const unsigned kb = ((unsigned)(s_) * 64u + (unsigned)klo * 2u) ^ sw;  \
                bf16x8 wF = __builtin_bit_cast(bf16x8, *(const u16x8*)((const char*)wlds + wbF + kb)); \
                bf16x8 wI = __builtin_bit_cast(bf16x8, *(const u16x8*)((const char*)wlds + wbI + kb)); \
                bf16x8 wC = __builtin_bit_cast(bf16x8, *(const u16x8*)((const char*)wlds + wbC + kb)); \
                bf16x8 wO = __builtin_bit_cast(bf16x8, *(const u16x8*)((const char*)wlds + wbO + kb)); \
                if ((s_) & 1) {                                                        \
                    oF = mfma16(wF, (av_), oF); oI = mfma16(wI, (av_), oI);            \
                    oC = mfma16(wC, (av_), oC); oO = mfma16(wO, (av_), oO);            \
                } else {                                                               \
                    eF = mfma16(wF, (av_), eF); eI = mfma16(wI, (av_), eI);            \
                    eC = mfma16(wC, (av_), eC); eO = mfma16(wO, (av_), eO);            \
                } } while (0)
            #define CONS_Q(s_, arr_, base_) do {                                       \
                u32x4 q_ = { (arr_)[(base_)], (arr_)[(base_)+1],                       \
                             (arr_)[(base_)+2], (arr_)[(base_)+3] };                   \
                bf16x8 av_ = __builtin_bit_cast(bf16x8, q_);                           \
                CONS(s_, av_); } while (0)

            if (layer) {
                const unsigned* hp = (const unsigned*)
                    (hx1b + (size_t)par * BATCH * KDIM + b * KDIM + klo);
                unsigned ahA[64], ahB[32], ahC[32];
                #pragma unroll
                for (int s = 0; s < 16; ++s)
                    #pragma unroll
                    for (int d = 0; d < 4; ++d)
                        ahA[s * 4 + d] = ld_coh32(hp + s * 16 + d);
                #pragma unroll
                for (int s = 16; s < 24; ++s)
                    #pragma unroll
                    for (int d = 0; d < 4; ++d)
                        ahB[(s - 16) * 4 + d] = ld_coh32(hp + s * 16 + d);
                #pragma unroll
                for (int s = 0; s < 16; ++s) CONS_Q(s, ahA, s * 4);
                #pragma unroll
                for (int s = 24; s < 32; ++s)
                    #pragma unroll
                    for (int d = 0; d < 4; ++d)
                        ahC[(s - 24) * 4 + d] = ld_coh32(hp + s * 16 + d);
                #pragma unroll
                for (int s = 16; s < 24; ++s) CONS_Q(s, ahB, (s - 16) * 4);
                #pragma unroll
                for (int s = 24; s < 32; ++s) CONS_Q(s, ahC, (s - 24) * 4);
            } else {
                const unsigned* hp = (const unsigned*)
                    (h0b + (size_t)par * BATCH * DH + b * DH + klo);
                unsigned ahA[64];
                #pragma unroll
                for (int s = 0; s < 16; ++s)
                    #pragma unroll
                    for (int d = 0; d < 4; ++d)
                        ahA[s * 4 + d] = ld_coh32(hp + s * 16 + d);
                // consume x-part from seq (normal cached loads) while h flies
                const float* sp = seq + ((size_t)t * BATCH + b) * DH + klo;
                #pragma unroll
                for (int s = 16; s < 32; ++s) {
                    float4 v0 = *(const float4*)(sp + (s - 16) * 32);
                    float4 v1 = *(const float4*)(sp + (s - 16) * 32 + 4);
                    u16x8 tv;
                    tv[0]=f2bf(v0.x); tv[1]=f2bf(v0.y); tv[2]=f2bf(v0.z); tv[3]=f2bf(v0.w);
                    tv[4]=f2bf(v1.x); tv[5]=f2bf(v1.y); tv[6]=f2bf(v1.z); tv[7]=f2bf(v1.w);
                    bf16x8 av = __builtin_bit_cast(bf16x8, tv);
                    CONS(s, av);
                }
                #pragma unroll
                for (int s = 0; s < 16; ++s) CONS_Q(s, ahA, s * 4);
            }
            #undef CONS_Q
            #undef CONS

            #pragma unroll
            for (int r = 0; r < 4; ++r) {
                float fg = sigmoid_f(eF[r] + oF[r] + bFa[r]);
                float ig = sigmoid_f(eI[r] + oI[r] + bIa[r]);
                float ct = tanh_f  (eC[r] + oC[r] + bCa[r]);
                float og = sigmoid_f(eO[r] + oO[r] + bOa[r]);
                float cn = fg * cs[r] + ig * ct;
                cs[r] = cn;
                hv[r]  = og * tanh_f(cn);
            }
            const unsigned d0 = (unsigned)f2bf(hv[0]) | ((unsigned)f2bf(hv[1]) << 16);
            const unsigned d1 = (unsigned)f2bf(hv[2]) | ((unsigned)f2bf(hv[3]) << 16);
            const int npar = (it + 1) & (NSLOT - 1);
            // h-stores only (write-through to coherence point) before publish
            if (!layer) {
                unsigned* p0 = (unsigned*)(h0b + (size_t)npar * BATCH * DH + b * DH + jq);
                st_coh32(p0, d0); st_coh32(p0 + 1, d1);
                unsigned* p1 = (unsigned*)(hx1b + (size_t)npar * BATCH * KDIM
                                                 + b * KDIM + DH + jq);
                st_coh32(p1, d0); st_coh32(p1 + 1, d1);
            } else {
                unsigned* p1 = (unsigned*)(hx1b + (size_t)npar * BATCH * KDIM
                                                 + b * KDIM + jq);
                st_coh32(p1, d0); st_coh32(p1 + 1, d1);
            }
        }

        // ---- publish EARLY: drain h-stores, flag up (out-stores come after) ----
        if (it < S_LEN) {
            __syncthreads();   // per-wave vmcnt(0): h-stores at coherence point
            if (tid == 0)
                st_coh32(&flags[wg * FLAG_STRIDE], (unsigned)(it + 1));
        }

        // ---- out-stores off the publish critical path ----
        if (active) {
            if (layer) {
                float* po = out + ((size_t)t * BATCH + b) * DH + jq;
                #pragma unroll
                for (int r = 0; r < 4; ++r) __builtin_nontemporal_store(hv[r], po + r);
                if (t == S_LEN - 1) {
                    float* pl = out + (size_t)S_LEN * BATCH * DH + (size_t)BATCH * DH
                                    + (size_t)b * DH + jq;
                    #pragma unroll
                    for (int r = 0; r < 4; ++r) __builtin_nontemporal_store(hv[r], pl + r);
                }
            } else if (t == S_LEN - 1) {
                float* po = out + (size_t)S_LEN * BATCH * DH + (size_t)b * DH + jq;
                #pragma unroll
                for (int r = 0; r < 4; ++r) __builtin_nontemporal_store(hv[r], po + r);
            }
        }

        // ---- decoupled per-layer rendezvous (tight poll, no sleep) ----
        if (it < S_LEN) {
            if (wave == 0) {
                unsigned need;
                if (lane < 32)      need = (unsigned)(it + 1);          // own layer
                else if (layer)     need = (unsigned)(it + 1);          // L1: L0 data dep
                else                need = (it >= 1) ? (unsigned)(it - 1) : 0u; // L0: WAR slack
                unsigned v = ld_coh32(pflag);
                while (!__all((int)(v >= need)))
                    v = ld_coh32(pflag);
            }
            __syncthreads();
            __builtin_amdgcn_sched_barrier(0);
        }
    }
}

extern "C" void kernel_launch(void* const* d_in, const int* in_sizes, int n_in,
                              void* d_out, int out_size, void* d_ws, size_t ws_size,
                              hipStream_t stream) {
    const float* seq    = (const float*)d_in[0];
    const float* h_init = (const float*)d_in[1];
    const float* Wf     = (const float*)d_in[2];
    const float* Bf     = (const float*)d_in[3];
    const float* Wi     = (const float*)d_in[4];
    const float* Bi     = (const float*)d_in[5];
    const float* Wc     = (const float*)d_in[6];
    const float* Bc     = (const float*)d_in[7];
    const float* Wo     = (const float*)d_in[8];
    const float* Bo     = (const float*)d_in[9];
    float* out          = (float*)d_out;
    unsigned short* ws  = (unsigned short*)d_ws;

    hipFuncSetAttribute((const void*)lstm_main,
                        hipFuncAttributeMaxDynamicSharedMemorySize, LDS_BYTES);

    hipLaunchKernelGGL(lstm_init, dim3(128), dim3(THREADS), 0, stream, seq, h_init, ws);

    void* args[] = { (void*)&seq,
                     (void*)&Wf, (void*)&Bf,
                     (void*)&Wi, (void*)&Bi,
                     (void*)&Wc, (void*)&Bc,
                     (void*)&Wo, (void*)&Bo,
                     (void*)&out, (void*)&ws };
    hipLaunchCooperativeKernel((void*)lstm_main, dim3(NWG), dim3(THREADS),
                               args, LDS_BYTES, stream);
}

// Round 12
// 3818.536 us; speedup vs baseline: 2.3224x; 2.2690x over previous
//
#include <hip/hip_runtime.h>
#include <hip/hip_bf16.h>

#define S_LEN   512
#define BATCH   64
#define DH      512
#define KDIM    1024      // 2*DH (concat [h, x])
#define NCOLS   64        // 4 gates * 16 units per WG
#define WGL     128       // WGs per layer
#define NWG     256
#define THREADS 256
#define NSLOT   4         // h rotation depth
#define FLAG_STRIDE 32    // uints: one flag per 128-B line
#define W_LDS_BYTES (NCOLS * KDIM * 2)           // 131072 weights
#define P_LDS_BYTES (16 * 64 * 16)               // 16384 partials (16 frags x 64 lanes x 16B)
#define LDS_BYTES   (W_LDS_BYTES + P_LDS_BYTES)  // 147456 <= 160K

typedef __attribute__((ext_vector_type(8))) unsigned short u16x8;
typedef __attribute__((ext_vector_type(8))) __bf16         bf16x8;
typedef __attribute__((ext_vector_type(4))) float          f32x4;
typedef __attribute__((ext_vector_type(4))) unsigned       u32x4;

__device__ __forceinline__ unsigned short f2bf(float f) {
    unsigned u = __float_as_uint(f);
    return (unsigned short)((u + 0x7fffu + ((u >> 16) & 1u)) >> 16);   // RNE
}
__device__ __forceinline__ float sigmoid_f(float x) { return 1.f / (1.f + __expf(-x)); }
__device__ __forceinline__ float tanh_f(float x) {
    float e = __expf(2.f * x);
    return 1.f - 2.f / (e + 1.f);
}
__device__ __forceinline__ f32x4 mfma16(bf16x8 a, bf16x8 b, f32x4 c) {
    return __builtin_amdgcn_mfma_f32_16x16x32_bf16(a, b, c, 0, 0, 0);
}
// 32-bit agent-scope relaxed atomics (proven instruction class, compiler-tracked).
__device__ __forceinline__ unsigned ld_coh32(const unsigned* p) {
    return __hip_atomic_load(p, __ATOMIC_RELAXED, __HIP_MEMORY_SCOPE_AGENT);
}
__device__ __forceinline__ void st_coh32(unsigned* p, unsigned v) {
    __hip_atomic_store(p, v, __ATOMIC_RELAXED, __HIP_MEMORY_SCOPE_AGENT);
}

// ws layout (ushort idx unless noted):
//   0      : h0[4][64][512] bf16  (256 KB)  layer0 h rotation
//   131072 : h1[4][64][512] bf16  (256 KB)  layer1 h rotation
//   byte 524288 : flags[256 * 32] uint      per-WG flag, one per 128-B line
#define WS_H0    0
#define WS_H1    (NSLOT * BATCH * DH)
#define WS_BAR_B 524288

__global__ void lstm_init(const float* __restrict__ seq,
                          const float* __restrict__ h_init,
                          unsigned short* __restrict__ ws) {
    int i = blockIdx.x * blockDim.x + threadIdx.x;   // 0 .. 32767
    unsigned* flags = (unsigned*)((char*)ws + WS_BAR_B);
    if (i < NWG) flags[i * FLAG_STRIDE] = 0;         // re-zeroed every launch
    if (i < BATCH * DH) {
        ws[WS_H0 + i] = f2bf(h_init[i]);                                 // h0 slot0
        ws[WS_H1 + BATCH * DH + i] = f2bf(h_init[(size_t)BATCH * DH + i]); // h1 slot1
    }
}

__global__ __launch_bounds__(THREADS, 1)
void lstm_main(const float* __restrict__ seq,
               const float* __restrict__ Wf, const float* __restrict__ Bf,
               const float* __restrict__ Wi, const float* __restrict__ Bi,
               const float* __restrict__ Wc, const float* __restrict__ Bc,
               const float* __restrict__ Wo, const float* __restrict__ Bo,
               float* __restrict__ out, unsigned short* __restrict__ ws)
{
    extern __shared__ unsigned short wlds[];   // weights [64][1024] bf16 swizzled, then partials
    float* plds = (float*)((char*)wlds + W_LDS_BYTES);   // [16 frag][64 lane][4] f32

    const int wg    = blockIdx.x;
    const int layer = wg >> 7;               // 0..1
    const int rid   = wg & (WGL - 1);        // 0..127
    const int us    = rid >> 2;              // unit-slice 0..31
    const int bg    = rid & 3;               // batch-group 0..3
    const int jbase = us * 16;
    const int bbase = bg * 16;
    const int tid   = threadIdx.x;
    const int lane  = tid & 63;
    const int wave  = tid >> 6;

    unsigned short* h0b = ws + WS_H0;
    unsigned short* h1b = ws + WS_H1;
    unsigned* flags = (unsigned*)((char*)ws + WS_BAR_B);

    // ---- stage this WG's weight slice into LDS (bf16, swizzled), once ----
    {
        const size_t woff = (size_t)layer * KDIM * DH;
        const float* Wg[4] = { Wf + woff, Wi + woff, Wc + woff, Wo + woff };
        for (int idx = tid; idx < NCOLS * KDIM; idx += THREADS) {
            int mcol = idx & (NCOLS - 1);          // gate*16 + unit
            int k    = idx >> 6;
            float w  = Wg[mcol >> 4][(size_t)k * DH + jbase + (mcol & 15)];
            unsigned byte = ((unsigned)mcol * 2048u + (unsigned)k * 2u)
                          ^ (((unsigned)mcol & 7u) << 4);
            wlds[byte >> 1] = f2bf(w);
        }
    }

    // MFMA geometry: A=weights (M=16 units), B=acts (N=16 batch).
    // D (m89): col = lane&15 -> batch-local, row = (lane>>4)*4+r -> unit-local.
    const int ln  = lane & 15;               // unit row (A) / batch col (B)
    const int lq  = lane >> 4;
    const int klo = lq * 8;
    const unsigned sw  = ((unsigned)(lane & 7)) << 4;
    const unsigned wbF = (0u * 16 + (unsigned)ln) * 2048u;
    const unsigned wbI = (1u * 16 + (unsigned)ln) * 2048u;
    const unsigned wbC = (2u * 16 + (unsigned)ln) * 2048u;
    const unsigned wbO = (3u * 16 + (unsigned)ln) * 2048u;

    // per-thread output cell: unit ul, batch bl  (256 threads = 16x16 cells)
    const int ul = tid & 15;
    const int bl = tid >> 4;
    const int lidx = (ul >> 2) * 16 + bl;    // source lane in D fragments
    const int ridx = ul & 3;                 // source reg in f32x4
    const float bF = Bf[layer * DH + jbase + ul];
    const float bI = Bi[layer * DH + jbase + ul];
    const float bC = Bc[layer * DH + jbase + ul];
    const float bO = Bo[layer * DH + jbase + ul];
    __syncthreads();

    float cs = 0.f;                          // cell state for (ul, bl)
    const bool useSeq = (!layer) && (wave >= 2);

    for (int it = 0; it <= S_LEN; ++it) {
        const bool active = layer ? (it >= 1) : (it < S_LEN);
        const int  t      = layer ? it - 1 : it;
        float hv = 0.f;

        if (active) {
            // ---- rendezvous (needs computed per flag's layer; flags monotonic) ----
            {
                const int f      = wave * 64 + lane;         // 0..255
                const int flayer = f >> 7;
                // L0@it needs: L0 >= it (h0(it-1) ready), L1 >= it-1 (WAR slack)
                // L1@it needs: L1 >= it-1 (h1(it-2) ready), L0 >= it (h0(it-1) = x)
                int needi = (flayer == 0) ? (layer ? it : it)
                                          : (layer ? it - 1 : it - 1);
                if (needi < 0) needi = 0;
                const unsigned need = (unsigned)needi;
                unsigned v = ld_coh32(&flags[f * FLAG_STRIDE]);
                while (!__all((int)(v >= need)))
                    v = ld_coh32(&flags[f * FLAG_STRIDE]);
            }
            __syncthreads();
            __builtin_amdgcn_sched_barrier(0);

            const int par = it & (NSLOT - 1);

            // ---- load this wave's K-slice of activations ----
            unsigned ah[32];
            if (!useSeq) {
                const unsigned short* hsrc = (wave < 2) ? (layer ? h1b : h0b) : h0b;
                const unsigned* hp = (const unsigned*)
                    (hsrc + (size_t)par * BATCH * DH + (size_t)(bbase + ln) * DH)
                    + ((wave & 1) * 256 + klo) / 2;
                #pragma unroll
                for (int c = 0; c < 8; ++c)
                    #pragma unroll
                    for (int d = 0; d < 4; ++d)
                        ah[c * 4 + d] = ld_coh32(hp + c * 16 + d);
            }

            // ---- 8 K-chunks x 4 gates MFMA (partial sums over K=256) ----
            f32x4 eF = {0,0,0,0}, eI = {0,0,0,0}, eC = {0,0,0,0}, eO = {0,0,0,0};
            f32x4 oF = {0,0,0,0}, oI = {0,0,0,0}, oC = {0,0,0,0}, oO = {0,0,0,0};
            const float* sp = useSeq
                ? seq + ((size_t)t * BATCH + bbase + ln) * DH + klo : nullptr;

            #pragma unroll
            for (int c = 0; c < 8; ++c) {
                const int s = wave * 8 + c;              // global K-chunk 0..31
                bf16x8 av;
                if (useSeq) {
                    float4 v0 = *(const float4*)(sp + (s - 16) * 32);
                    float4 v1 = *(const float4*)(sp + (s - 16) * 32 + 4);
                    u16x8 tv;
                    tv[0]=f2bf(v0.x); tv[1]=f2bf(v0.y); tv[2]=f2bf(v0.z); tv[3]=f2bf(v0.w);
                    tv[4]=f2bf(v1.x); tv[5]=f2bf(v1.y); tv[6]=f2bf(v1.z); tv[7]=f2bf(v1.w);
                    av = __builtin_bit_cast(bf16x8, tv);
                } else {
                    u32x4 q = { ah[c*4], ah[c*4+1], ah[c*4+2], ah[c*4+3] };
                    av = __builtin_bit_cast(bf16x8, q);
                }
                const unsigned kb = ((unsigned)s * 64u + (unsigned)klo * 2u) ^ sw;
                bf16x8 wF = __builtin_bit_cast(bf16x8, *(const u16x8*)((const char*)wlds + wbF + kb));
                bf16x8 wI = __builtin_bit_cast(bf16x8, *(const u16x8*)((const char*)wlds + wbI + kb));
                bf16x8 wC = __builtin_bit_cast(bf16x8, *(const u16x8*)((const char*)wlds + wbC + kb));
                bf16x8 wO = __builtin_bit_cast(bf16x8, *(const u16x8*)((const char*)wlds + wbO + kb));
                if (c & 1) {
                    oF = mfma16(wF, av, oF); oI = mfma16(wI, av, oI);
                    oC = mfma16(wC, av, oC); oO = mfma16(wO, av, oO);
                } else {
                    eF = mfma16(wF, av, eF); eI = mfma16(wI, av, eI);
                    eC = mfma16(wC, av, eC); eO = mfma16(wO, av, eO);
                }
            }
            f32x4 pF = eF + oF, pI = eI + oI, pC = eC + oC, pO = eO + oO;

            // ---- cross-wave K-reduction via LDS ----
            f32x4* pv = (f32x4*)plds;
            pv[(wave * 4 + 0) * 64 + lane] = pF;
            pv[(wave * 4 + 1) * 64 + lane] = pI;
            pv[(wave * 4 + 2) * 64 + lane] = pC;
            pv[(wave * 4 + 3) * 64 + lane] = pO;
            __syncthreads();

            float sF = 0.f, sI = 0.f, sC = 0.f, sO = 0.f;
            #pragma unroll
            for (int w = 0; w < 4; ++w) {
                sF += plds[((w * 4 + 0) * 64 + lidx) * 4 + ridx];
                sI += plds[((w * 4 + 1) * 64 + lidx) * 4 + ridx];
                sC += plds[((w * 4 + 2) * 64 + lidx) * 4 + ridx];
                sO += plds[((w * 4 + 3) * 64 + lidx) * 4 + ridx];
            }

            const float fg = sigmoid_f(sF + bF);
            const float ig = sigmoid_f(sI + bI);
            const float ct = tanh_f  (sC + bC);
            const float og = sigmoid_f(sO + bO);
            const float cn = fg * cs + ig * ct;
            cs = cn;
            hv = og * tanh_f(cn);

            // ---- h-store: pack unit pairs, write-through (single destination) ----
            const unsigned hb16  = (unsigned)f2bf(hv);
            const unsigned other = (unsigned)__shfl_xor((int)hb16, 1, 64);
            const int npar = (it + 1) & (NSLOT - 1);
            if (!(ul & 1)) {
                unsigned dw = hb16 | (other << 16);
                unsigned short* dst = (layer ? h1b : h0b)
                    + (size_t)npar * BATCH * DH + (size_t)(bbase + bl) * DH + jbase + ul;
                st_coh32((unsigned*)dst, dw);
            }
        }

        // ---- publish EARLY (h-stores drained by syncthreads), out after ----
        if (active) {
            __syncthreads();
            if (tid == 0)
                st_coh32(&flags[wg * FLAG_STRIDE], (unsigned)(it + 1));

            if (layer) {
                __builtin_nontemporal_store(hv,
                    out + ((size_t)t * BATCH + bbase + bl) * DH + jbase + ul);
                if (t == S_LEN - 1)
                    __builtin_nontemporal_store(hv,
                        out + (size_t)S_LEN * BATCH * DH + (size_t)BATCH * DH
                            + (size_t)(bbase + bl) * DH + jbase + ul);
            } else if (t == S_LEN - 1) {
                __builtin_nontemporal_store(hv,
                    out + (size_t)S_LEN * BATCH * DH
                        + (size_t)(bbase + bl) * DH + jbase + ul);
            }
        }
    }
}

extern "C" void kernel_launch(void* const* d_in, const int* in_sizes, int n_in,
                              void* d_out, int out_size, void* d_ws, size_t ws_size,
                              hipStream_t stream) {
    const float* seq    = (const float*)d_in[0];
    const float* h_init = (const float*)d_in[1];
    const float* Wf     = (const float*)d_in[2];
    const float* Bf     = (const float*)d_in[3];
    const float* Wi     = (const float*)d_in[4];
    const float* Bi     = (const float*)d_in[5];
    const float* Wc     = (const float*)d_in[6];
    const float* Bc     = (const float*)d_in[7];
    const float* Wo     = (const float*)d_in[8];
    const float* Bo     = (const float*)d_in[9];
    float* out          = (float*)d_out;
    unsigned short* ws  = (unsigned short*)d_ws;

    hipFuncSetAttribute((const void*)lstm_main,
                        hipFuncAttributeMaxDynamicSharedMemorySize, LDS_BYTES);

    hipLaunchKernelGGL(lstm_init, dim3(128), dim3(THREADS), 0, stream, seq, h_init, ws);

    void* args[] = { (void*)&seq,
                     (void*)&Wf, (void*)&Bf,
                     (void*)&Wi, (void*)&Bi,
                     (void*)&Wc, (void*)&Bc,
                     (void*)&Wo, (void*)&Bo,
                     (void*)&out, (void*)&ws };
    hipLaunchCooperativeKernel((void*)lstm_main, dim3(NWG), dim3(THREADS),
                               args, LDS_BYTES, stream);
}

// Round 13
// 3492.200 us; speedup vs baseline: 2.5394x; 1.0934x over previous
//
#include <hip/hip_runtime.h>
#include <hip/hip_bf16.h>

#define S_LEN   512
#define BATCH   64
#define DH      512
#define KDIM    1024      // 2*DH (concat [h, x])
#define NCOLS   64        // 4 gates * 16 units per WG
#define WGL     128       // WGs per layer
#define NWG     256
#define THREADS 256
#define NSLOT   4         // h rotation depth
#define FLAG_STRIDE 32    // uints: one flag per 128-B line
#define W_LDS_BYTES (NCOLS * KDIM * 2)           // 131072 weights
#define P_LDS_BYTES (16 * 64 * 16)               // 16384 partials
#define LDS_BYTES   (W_LDS_BYTES + P_LDS_BYTES)  // 147456 <= 160K

typedef __attribute__((ext_vector_type(8))) unsigned short u16x8;
typedef __attribute__((ext_vector_type(8))) __bf16         bf16x8;
typedef __attribute__((ext_vector_type(4))) float          f32x4;
typedef __attribute__((ext_vector_type(4))) unsigned       u32x4;

__device__ __forceinline__ unsigned short f2bf(float f) {
    unsigned u = __float_as_uint(f);
    return (unsigned short)((u + 0x7fffu + ((u >> 16) & 1u)) >> 16);   // RNE
}
__device__ __forceinline__ float sigmoid_f(float x) { return 1.f / (1.f + __expf(-x)); }
__device__ __forceinline__ float tanh_f(float x) {
    float e = __expf(2.f * x);
    return 1.f - 2.f / (e + 1.f);
}
__device__ __forceinline__ f32x4 mfma16(bf16x8 a, bf16x8 b, f32x4 c) {
    return __builtin_amdgcn_mfma_f32_16x16x32_bf16(a, b, c, 0, 0, 0);
}
// 32-bit agent-scope relaxed atomics (proven instruction class, compiler-tracked).
__device__ __forceinline__ unsigned ld_coh32(const unsigned* p) {
    return __hip_atomic_load(p, __ATOMIC_RELAXED, __HIP_MEMORY_SCOPE_AGENT);
}
__device__ __forceinline__ void st_coh32(unsigned* p, unsigned v) {
    __hip_atomic_store(p, v, __ATOMIC_RELAXED, __HIP_MEMORY_SCOPE_AGENT);
}

// ws layout (ushort idx unless noted):
//   0      : h0[4][64][512] bf16  (256 KB)  layer0 h rotation
//   131072 : h1[4][64][512] bf16  (256 KB)  layer1 h rotation
//   byte 524288 : flags[256 * 32] uint      per-WG flag, one per 128-B line
#define WS_H0    0
#define WS_H1    (NSLOT * BATCH * DH)
#define WS_BAR_B 524288

__global__ void lstm_init(const float* __restrict__ seq,
                          const float* __restrict__ h_init,
                          unsigned short* __restrict__ ws) {
    int i = blockIdx.x * blockDim.x + threadIdx.x;   // 0 .. 32767
    unsigned* flags = (unsigned*)((char*)ws + WS_BAR_B);
    if (i < NWG) flags[i * FLAG_STRIDE] = 0;         // re-zeroed every launch
    if (i < BATCH * DH) {
        ws[WS_H0 + i] = f2bf(h_init[i]);                                   // h0 slot0
        ws[WS_H1 + BATCH * DH + i] = f2bf(h_init[(size_t)BATCH * DH + i]); // h1 slot1
    }
}

__global__ __launch_bounds__(THREADS, 1)
void lstm_main(const float* __restrict__ seq,
               const float* __restrict__ Wf, const float* __restrict__ Bf,
               const float* __restrict__ Wi, const float* __restrict__ Bi,
               const float* __restrict__ Wc, const float* __restrict__ Bc,
               const float* __restrict__ Wo, const float* __restrict__ Bo,
               float* __restrict__ out, unsigned short* __restrict__ ws)
{
    extern __shared__ unsigned short wlds[];   // weights [64][1024] bf16 swizzled
    float* plds = (float*)((char*)wlds + W_LDS_BYTES);   // [16 frag][64 lane][4] f32

    const int wg    = blockIdx.x;
    const int layer = wg >> 7;               // 0..1
    const int rid   = wg & (WGL - 1);        // 0..127
    const int us    = rid >> 2;              // unit-slice 0..31
    const int bg    = rid & 3;               // batch-group 0..3
    const int jbase = us * 16;
    const int bbase = bg * 16;
    const int tid   = threadIdx.x;
    const int lane  = tid & 63;
    const int wave  = tid >> 6;

    unsigned short* h0b = ws + WS_H0;
    unsigned short* h1b = ws + WS_H1;
    unsigned* flags = (unsigned*)((char*)ws + WS_BAR_B);

    // ---- stage this WG's weight slice into LDS (bf16, swizzled), once ----
    {
        const size_t woff = (size_t)layer * KDIM * DH;
        const float* Wg[4] = { Wf + woff, Wi + woff, Wc + woff, Wo + woff };
        for (int idx = tid; idx < NCOLS * KDIM; idx += THREADS) {
            int mcol = idx & (NCOLS - 1);          // gate*16 + unit
            int k    = idx >> 6;
            float w  = Wg[mcol >> 4][(size_t)k * DH + jbase + (mcol & 15)];
            unsigned byte = ((unsigned)mcol * 2048u + (unsigned)k * 2u)
                          ^ (((unsigned)mcol & 7u) << 4);
            wlds[byte >> 1] = f2bf(w);
        }
    }

    // MFMA geometry: A=weights (M=16 units), B=acts (N=16 batch).
    // D (m89): col = lane&15 -> batch-local, row = (lane>>4)*4+r -> unit-local.
    const int ln  = lane & 15;
    const int lq  = lane >> 4;
    const int klo = lq * 8;
    const unsigned sw  = ((unsigned)(lane & 7)) << 4;
    const unsigned wbF = (0u * 16 + (unsigned)ln) * 2048u;
    const unsigned wbI = (1u * 16 + (unsigned)ln) * 2048u;
    const unsigned wbC = (2u * 16 + (unsigned)ln) * 2048u;
    const unsigned wbO = (3u * 16 + (unsigned)ln) * 2048u;

    // per-thread output cell: unit ul, batch bl  (256 threads = 16x16 cells)
    const int ul = tid & 15;
    const int bl = tid >> 4;
    const int lidx = (ul >> 2) * 16 + bl;    // source lane in D fragments
    const int ridx = ul & 3;                 // source reg in f32x4
    const float bF = Bf[layer * DH + jbase + ul];
    const float bI = Bi[layer * DH + jbase + ul];
    const float bC = Bc[layer * DH + jbase + ul];
    const float bO = Bo[layer * DH + jbase + ul];

    // ---- per-wave poll target: the 64 producers of THIS wave's K-slice ----
    // L0: w0/w1 -> L0 flags[0-63]/[64-127] (h-part); w2/w3 -> L1 flags (WAR only)
    // L1: w0/w1 -> L1 flags[128-191]/[192-255] (h-part); w2/w3 -> L0 flags (x-part)
    const int pw = layer ? ((wave + 2) & 3) : wave;
    const unsigned* pflag = &flags[(pw * 64 + lane) * FLAG_STRIDE];
    __syncthreads();

    float cs = 0.f;                          // cell state for (ul, bl)
    const bool useSeq = (!layer) && (wave >= 2);

    for (int it = 0; it <= S_LEN; ++it) {
        const bool active = layer ? (it >= 1) : (it < S_LEN);
        const int  t      = layer ? it - 1 : it;
        float hv = 0.f;

        if (active) {
            // ---- per-wave decoupled wait ----
            {
                int needi;
                if (!layer) needi = (wave < 2) ? it : (it - 2);          // h-dep / WAR
                else        needi = (wave < 2) ? ((it <= 1) ? 0 : it)    // h1-dep (race-fixed)
                                               : it;                     // x = h0 dep
                if (needi < 0) needi = 0;
                const unsigned need = (unsigned)needi;
                unsigned v = ld_coh32(pflag);
                while (!__all((int)(v >= need)))
                    v = ld_coh32(pflag);
            }
            __builtin_amdgcn_sched_barrier(0);

            const int par = it & (NSLOT - 1);

            // ---- load this wave's K-slice of activations ----
            unsigned ah[32];
            if (!useSeq) {
                const unsigned short* hsrc = (wave < 2) ? (layer ? h1b : h0b) : h0b;
                const unsigned* hp = (const unsigned*)
                    (hsrc + (size_t)par * BATCH * DH + (size_t)(bbase + ln) * DH)
                    + ((wave & 1) * 256 + klo) / 2;
                #pragma unroll
                for (int c = 0; c < 8; ++c)
                    #pragma unroll
                    for (int d = 0; d < 4; ++d)
                        ah[c * 4 + d] = ld_coh32(hp + c * 16 + d);
            }

            // ---- 8 K-chunks x 4 gates MFMA (partial sums over K=256) ----
            f32x4 eF = {0,0,0,0}, eI = {0,0,0,0}, eC = {0,0,0,0}, eO = {0,0,0,0};
            f32x4 oF = {0,0,0,0}, oI = {0,0,0,0}, oC = {0,0,0,0}, oO = {0,0,0,0};
            const float* sp = useSeq
                ? seq + ((size_t)t * BATCH + bbase + ln) * DH + klo : nullptr;

            #pragma unroll
            for (int c = 0; c < 8; ++c) {
                const int s = wave * 8 + c;              // global K-chunk 0..31
                bf16x8 av;
                if (useSeq) {
                    float4 v0 = *(const float4*)(sp + (s - 16) * 32);
                    float4 v1 = *(const float4*)(sp + (s - 16) * 32 + 4);
                    u16x8 tv;
                    tv[0]=f2bf(v0.x); tv[1]=f2bf(v0.y); tv[2]=f2bf(v0.z); tv[3]=f2bf(v0.w);
                    tv[4]=f2bf(v1.x); tv[5]=f2bf(v1.y); tv[6]=f2bf(v1.z); tv[7]=f2bf(v1.w);
                    av = __builtin_bit_cast(bf16x8, tv);
                } else {
                    u32x4 q = { ah[c*4], ah[c*4+1], ah[c*4+2], ah[c*4+3] };
                    av = __builtin_bit_cast(bf16x8, q);
                }
                const unsigned kb = ((unsigned)s * 64u + (unsigned)klo * 2u) ^ sw;
                bf16x8 wF = __builtin_bit_cast(bf16x8, *(const u16x8*)((const char*)wlds + wbF + kb));
                bf16x8 wI = __builtin_bit_cast(bf16x8, *(const u16x8*)((const char*)wlds + wbI + kb));
                bf16x8 wC = __builtin_bit_cast(bf16x8, *(const u16x8*)((const char*)wlds + wbC + kb));
                bf16x8 wO = __builtin_bit_cast(bf16x8, *(const u16x8*)((const char*)wlds + wbO + kb));
                if (c & 1) {
                    oF = mfma16(wF, av, oF); oI = mfma16(wI, av, oI);
                    oC = mfma16(wC, av, oC); oO = mfma16(wO, av, oO);
                } else {
                    eF = mfma16(wF, av, eF); eI = mfma16(wI, av, eI);
                    eC = mfma16(wC, av, eC); eO = mfma16(wO, av, eO);
                }
            }
            f32x4 pF = eF + oF, pI = eI + oI, pC = eC + oC, pO = eO + oO;

            // ---- cross-wave K-reduction via LDS (join point of all waves) ----
            f32x4* pv = (f32x4*)plds;
            pv[(wave * 4 + 0) * 64 + lane] = pF;
            pv[(wave * 4 + 1) * 64 + lane] = pI;
            pv[(wave * 4 + 2) * 64 + lane] = pC;
            pv[(wave * 4 + 3) * 64 + lane] = pO;
            __syncthreads();

            float sF = 0.f, sI = 0.f, sC = 0.f, sO = 0.f;
            #pragma unroll
            for (int w = 0; w < 4; ++w) {
                sF += plds[((w * 4 + 0) * 64 + lidx) * 4 + ridx];
                sI += plds[((w * 4 + 1) * 64 + lidx) * 4 + ridx];
                sC += plds[((w * 4 + 2) * 64 + lidx) * 4 + ridx];
                sO += plds[((w * 4 + 3) * 64 + lidx) * 4 + ridx];
            }

            const float fg = sigmoid_f(sF + bF);
            const float ig = sigmoid_f(sI + bI);
            const float ct = tanh_f  (sC + bC);
            const float og = sigmoid_f(sO + bO);
            const float cn = fg * cs + ig * ct;
            cs = cn;
            hv = og * tanh_f(cn);

            // ---- h-store: pack unit pairs, write-through (single destination) ----
            const unsigned hb16  = (unsigned)f2bf(hv);
            const unsigned other = (unsigned)__shfl_xor((int)hb16, 1, 64);
            const int npar = (it + 1) & (NSLOT - 1);
            if (!(ul & 1)) {
                unsigned dw = hb16 | (other << 16);
                unsigned short* dst = (layer ? h1b : h0b)
                    + (size_t)npar * BATCH * DH + (size_t)(bbase + bl) * DH + jbase + ul;
                st_coh32((unsigned*)dst, dw);
            }

            // ---- publish EARLY (h-stores drained by syncthreads), out after ----
            __syncthreads();
            if (tid == 0)
                st_coh32(&flags[wg * FLAG_STRIDE], (unsigned)(it + 1));

            if (layer) {
                __builtin_nontemporal_store(hv,
                    out + ((size_t)t * BATCH + bbase + bl) * DH + jbase + ul);
                if (t == S_LEN - 1)
                    __builtin_nontemporal_store(hv,
                        out + (size_t)S_LEN * BATCH * DH + (size_t)BATCH * DH
                            + (size_t)(bbase + bl) * DH + jbase + ul);
            } else if (t == S_LEN - 1) {
                __builtin_nontemporal_store(hv,
                    out + (size_t)S_LEN * BATCH * DH
                        + (size_t)(bbase + bl) * DH + jbase + ul);
            }
        }
    }
}

extern "C" void kernel_launch(void* const* d_in, const int* in_sizes, int n_in,
                              void* d_out, int out_size, void* d_ws, size_t ws_size,
                              hipStream_t stream) {
    const float* seq    = (const float*)d_in[0];
    const float* h_init = (const float*)d_in[1];
    const float* Wf     = (const float*)d_in[2];
    const float* Bf     = (const float*)d_in[3];
    const float* Wi     = (const float*)d_in[4];
    const float* Bi     = (const float*)d_in[5];
    const float* Wc     = (const float*)d_in[6];
    const float* Bc     = (const float*)d_in[7];
    const float* Wo     = (const float*)d_in[8];
    const float* Bo     = (const float*)d_in[9];
    float* out          = (float*)d_out;
    unsigned short* ws  = (unsigned short*)d_ws;

    hipFuncSetAttribute((const void*)lstm_main,
                        hipFuncAttributeMaxDynamicSharedMemorySize, LDS_BYTES);

    hipLaunchKernelGGL(lstm_init, dim3(128), dim3(THREADS), 0, stream, seq, h_init, ws);

    void* args[] = { (void*)&seq,
                     (void*)&Wf, (void*)&Bf,
                     (void*)&Wi, (void*)&Bi,
                     (void*)&Wc, (void*)&Bc,
                     (void*)&Wo, (void*)&Bo,
                     (void*)&out, (void*)&ws };
    hipLaunchCooperativeKernel((void*)lstm_main, dim3(NWG), dim3(THREADS),
                               args, LDS_BYTES, stream);
}

// Round 14
// 3302.112 us; speedup vs baseline: 2.6856x; 1.0576x over previous
//
#include <hip/hip_runtime.h>
#include <hip/hip_bf16.h>

#define S_LEN   512
#define BATCH   64
#define DH      512
#define KDIM    1024      // 2*DH (concat [h, x])
#define NCOLS   64        // 4 gates * 16 units per WG
#define WGL     128       // WGs per layer
#define NWG     256
#define THREADS 256
#define NSLOT   4         // h rotation depth
#define FLAG_STRIDE 32    // uints: one flag per 128-B line
#define W_LDS_BYTES (NCOLS * KDIM * 2)           // 131072 weights
#define P_LDS_BYTES (16 * 64 * 16)               // 16384 partials
#define LDS_BYTES   (W_LDS_BYTES + P_LDS_BYTES)  // 147456 <= 160K

typedef __attribute__((ext_vector_type(8))) unsigned short u16x8;
typedef __attribute__((ext_vector_type(8))) __bf16         bf16x8;
typedef __attribute__((ext_vector_type(4))) float          f32x4;
typedef __attribute__((ext_vector_type(4))) unsigned       u32x4;

__device__ __forceinline__ unsigned short f2bf(float f) {
    unsigned u = __float_as_uint(f);
    return (unsigned short)((u + 0x7fffu + ((u >> 16) & 1u)) >> 16);   // RNE
}
__device__ __forceinline__ float sigmoid_f(float x) { return 1.f / (1.f + __expf(-x)); }
__device__ __forceinline__ float tanh_f(float x) {
    float e = __expf(2.f * x);
    return 1.f - 2.f / (e + 1.f);
}
__device__ __forceinline__ f32x4 mfma16(bf16x8 a, bf16x8 b, f32x4 c) {
    return __builtin_amdgcn_mfma_f32_16x16x32_bf16(a, b, c, 0, 0, 0);
}
// 32-bit agent-scope relaxed atomics (proven instruction class, compiler-tracked).
__device__ __forceinline__ unsigned ld_coh32(const unsigned* p) {
    return __hip_atomic_load(p, __ATOMIC_RELAXED, __HIP_MEMORY_SCOPE_AGENT);
}
__device__ __forceinline__ void st_coh32(unsigned* p, unsigned v) {
    __hip_atomic_store(p, v, __ATOMIC_RELAXED, __HIP_MEMORY_SCOPE_AGENT);
}

// ws layout (ushort idx unless noted):
//   0      : h0[4][64][512] bf16  (256 KB)  layer0 h rotation
//   131072 : h1[4][64][512] bf16  (256 KB)  layer1 h rotation
//   byte 524288 : flags[256 * 32] uint      per-WG flag, one per 128-B line
#define WS_H0    0
#define WS_H1    (NSLOT * BATCH * DH)
#define WS_BAR_B 524288

__global__ void lstm_init(const float* __restrict__ seq,
                          const float* __restrict__ h_init,
                          unsigned short* __restrict__ ws) {
    int i = blockIdx.x * blockDim.x + threadIdx.x;   // 0 .. 32767
    unsigned* flags = (unsigned*)((char*)ws + WS_BAR_B);
    if (i < NWG) flags[i * FLAG_STRIDE] = 0;         // re-zeroed every launch
    if (i < BATCH * DH) {
        ws[WS_H0 + i] = f2bf(h_init[i]);                                   // h0 slot0
        ws[WS_H1 + BATCH * DH + i] = f2bf(h_init[(size_t)BATCH * DH + i]); // h1 slot1
    }
}

__global__ __launch_bounds__(THREADS, 1)
void lstm_main(const float* __restrict__ seq,
               const float* __restrict__ Wf, const float* __restrict__ Bf,
               const float* __restrict__ Wi, const float* __restrict__ Bi,
               const float* __restrict__ Wc, const float* __restrict__ Bc,
               const float* __restrict__ Wo, const float* __restrict__ Bo,
               float* __restrict__ out, unsigned short* __restrict__ ws)
{
    extern __shared__ unsigned short wlds[];   // weights [64][1024] bf16 swizzled
    float* plds = (float*)((char*)wlds + W_LDS_BYTES);   // [16 frag][64 lane][4] f32

    const int wg    = blockIdx.x;
    const int layer = wg >> 7;               // 0..1
    const int rid   = wg & (WGL - 1);        // 0..127
    const int us    = rid >> 2;              // unit-slice 0..31
    const int bg    = rid & 3;               // batch-group 0..3
    const int jbase = us * 16;
    const int bbase = bg * 16;
    const int tid   = threadIdx.x;
    const int lane  = tid & 63;
    const int wave  = tid >> 6;

    unsigned short* h0b = ws + WS_H0;
    unsigned short* h1b = ws + WS_H1;
    unsigned* flags = (unsigned*)((char*)ws + WS_BAR_B);

    // ---- stage this WG's weight slice into LDS (bf16, swizzled), once ----
    {
        const size_t woff = (size_t)layer * KDIM * DH;
        const float* Wg[4] = { Wf + woff, Wi + woff, Wc + woff, Wo + woff };
        for (int idx = tid; idx < NCOLS * KDIM; idx += THREADS) {
            int mcol = idx & (NCOLS - 1);          // gate*16 + unit
            int k    = idx >> 6;
            float w  = Wg[mcol >> 4][(size_t)k * DH + jbase + (mcol & 15)];
            unsigned byte = ((unsigned)mcol * 2048u + (unsigned)k * 2u)
                          ^ (((unsigned)mcol & 7u) << 4);
            wlds[byte >> 1] = f2bf(w);
        }
    }

    // MFMA geometry: A=weights (M=16 units), B=acts (N=16 batch).
    // D (m89): col = lane&15 -> batch-local, row = (lane>>4)*4+r -> unit-local.
    const int ln  = lane & 15;
    const int lq  = lane >> 4;
    const int klo = lq * 8;
    const unsigned sw  = ((unsigned)(lane & 7)) << 4;
    const unsigned wbF = (0u * 16 + (unsigned)ln) * 2048u;
    const unsigned wbI = (1u * 16 + (unsigned)ln) * 2048u;
    const unsigned wbC = (2u * 16 + (unsigned)ln) * 2048u;
    const unsigned wbO = (3u * 16 + (unsigned)ln) * 2048u;

    // per-thread output cell: unit ul, batch bl  (256 threads = 16x16 cells)
    const int ul = tid & 15;
    const int bl = tid >> 4;
    const int lidx = (ul >> 2) * 16 + bl;    // source lane in D fragments
    const int ridx = ul & 3;                 // source reg in f32x4
    const float bF = Bf[layer * DH + jbase + ul];
    const float bI = Bi[layer * DH + jbase + ul];
    const float bC = Bc[layer * DH + jbase + ul];
    const float bO = Bo[layer * DH + jbase + ul];

    // ---- EXACT producer poll set (16 WGs; 32 for the WAR edge) ----
    // A consumer wave reads rows [bg*16,+16) of a 256-col K-slice, which only
    // producer WGs with the SAME bg and us in [16*w, 16*w+16) write. flag idx
    // of WG (L,us,bg) = L*128 + us*4 + bg. Batch-groups form 4 fully
    // independent dependency domains -> no cross-bg straggler coupling, and
    // 4x fewer poll lines than r13 (MALL queue pressure down).
    int fl;
    if (!layer) {
        if (wave < 2) fl =       ((wave * 16 + ln) << 2) + bg;            // L0 self
        else          fl = 128 + ((lane & 31) << 2) + bg;                 // L1 WAR (32)
    } else {
        if (wave < 2) fl = 128 + ((wave * 16 + ln) << 2) + bg;            // L1 self
        else          fl =       (((wave - 2) * 16 + ln) << 2) + bg;      // L0 x-dep
    }
    const unsigned* pflag = &flags[fl * FLAG_STRIDE];
    __syncthreads();

    float cs = 0.f;                          // cell state for (ul, bl)
    const bool useSeq = (!layer) && (wave >= 2);

    for (int it = 0; it <= S_LEN; ++it) {
        const bool active = layer ? (it >= 1) : (it < S_LEN);
        const int  t      = layer ? it - 1 : it;
        float hv = 0.f;

        if (active) {
            // ---- per-wave decoupled wait over the exact producer set ----
            {
                int needi;
                if (!layer) needi = (wave < 2) ? it : (it - 2);          // h-dep / WAR
                else        needi = (wave < 2) ? ((it <= 1) ? 0 : it)    // h1-dep
                                               : it;                     // x = h0 dep
                if (needi < 0) needi = 0;
                const unsigned need = (unsigned)needi;
                unsigned v = ld_coh32(pflag);
                while (!__all((int)(v >= need)))
                    v = ld_coh32(pflag);
            }
            __builtin_amdgcn_sched_barrier(0);

            const int par = it & (NSLOT - 1);

            // ---- load this wave's K-slice of activations ----
            unsigned ah[32];
            if (!useSeq) {
                const unsigned short* hsrc = (wave < 2) ? (layer ? h1b : h0b) : h0b;
                const unsigned* hp = (const unsigned*)
                    (hsrc + (size_t)par * BATCH * DH + (size_t)(bbase + ln) * DH)
                    + ((wave & 1) * 256 + klo) / 2;
                #pragma unroll
                for (int c = 0; c < 8; ++c)
                    #pragma unroll
                    for (int d = 0; d < 4; ++d)
                        ah[c * 4 + d] = ld_coh32(hp + c * 16 + d);
            }

            // ---- 8 K-chunks x 4 gates MFMA (partial sums over K=256) ----
            f32x4 eF = {0,0,0,0}, eI = {0,0,0,0}, eC = {0,0,0,0}, eO = {0,0,0,0};
            f32x4 oF = {0,0,0,0}, oI = {0,0,0,0}, oC = {0,0,0,0}, oO = {0,0,0,0};
            const float* sp = useSeq
                ? seq + ((size_t)t * BATCH + bbase + ln) * DH + klo : nullptr;

            #pragma unroll
            for (int c = 0; c < 8; ++c) {
                const int s = wave * 8 + c;              // global K-chunk 0..31
                bf16x8 av;
                if (useSeq) {
                    float4 v0 = *(const float4*)(sp + (s - 16) * 32);
                    float4 v1 = *(const float4*)(sp + (s - 16) * 32 + 4);
                    u16x8 tv;
                    tv[0]=f2bf(v0.x); tv[1]=f2bf(v0.y); tv[2]=f2bf(v0.z); tv[3]=f2bf(v0.w);
                    tv[4]=f2bf(v1.x); tv[5]=f2bf(v1.y); tv[6]=f2bf(v1.z); tv[7]=f2bf(v1.w);
                    av = __builtin_bit_cast(bf16x8, tv);
                } else {
                    u32x4 q = { ah[c*4], ah[c*4+1], ah[c*4+2], ah[c*4+3] };
                    av = __builtin_bit_cast(bf16x8, q);
                }
                const unsigned kb = ((unsigned)s * 64u + (unsigned)klo * 2u) ^ sw;
                bf16x8 wF = __builtin_bit_cast(bf16x8, *(const u16x8*)((const char*)wlds + wbF + kb));
                bf16x8 wI = __builtin_bit_cast(bf16x8, *(const u16x8*)((const char*)wlds + wbI + kb));
                bf16x8 wC = __builtin_bit_cast(bf16x8, *(const u16x8*)((const char*)wlds + wbC + kb));
                bf16x8 wO = __builtin_bit_cast(bf16x8, *(const u16x8*)((const char*)wlds + wbO + kb));
                if (c & 1) {
                    oF = mfma16(wF, av, oF); oI = mfma16(wI, av, oI);
                    oC = mfma16(wC, av, oC); oO = mfma16(wO, av, oO);
                } else {
                    eF = mfma16(wF, av, eF); eI = mfma16(wI, av, eI);
                    eC = mfma16(wC, av, eC); eO = mfma16(wO, av, eO);
                }
            }
            f32x4 pF = eF + oF, pI = eI + oI, pC = eC + oC, pO = eO + oO;

            // ---- cross-wave K-reduction via LDS (join point of all waves) ----
            f32x4* pv = (f32x4*)plds;
            pv[(wave * 4 + 0) * 64 + lane] = pF;
            pv[(wave * 4 + 1) * 64 + lane] = pI;
            pv[(wave * 4 + 2) * 64 + lane] = pC;
            pv[(wave * 4 + 3) * 64 + lane] = pO;
            __syncthreads();

            float sF = 0.f, sI = 0.f, sC = 0.f, sO = 0.f;
            #pragma unroll
            for (int w = 0; w < 4; ++w) {
                sF += plds[((w * 4 + 0) * 64 + lidx) * 4 + ridx];
                sI += plds[((w * 4 + 1) * 64 + lidx) * 4 + ridx];
                sC += plds[((w * 4 + 2) * 64 + lidx) * 4 + ridx];
                sO += plds[((w * 4 + 3) * 64 + lidx) * 4 + ridx];
            }

            const float fg = sigmoid_f(sF + bF);
            const float ig = sigmoid_f(sI + bI);
            const float ct = tanh_f  (sC + bC);
            const float og = sigmoid_f(sO + bO);
            const float cn = fg * cs + ig * ct;
            cs = cn;
            hv = og * tanh_f(cn);

            // ---- h-store: pack unit pairs, write-through (single destination) ----
            const unsigned hb16  = (unsigned)f2bf(hv);
            const unsigned other = (unsigned)__shfl_xor((int)hb16, 1, 64);
            const int npar = (it + 1) & (NSLOT - 1);
            if (!(ul & 1)) {
                unsigned dw = hb16 | (other << 16);
                unsigned short* dst = (layer ? h1b : h0b)
                    + (size_t)npar * BATCH * DH + (size_t)(bbase + bl) * DH + jbase + ul;
                st_coh32((unsigned*)dst, dw);
            }

            // ---- publish EARLY (h-stores drained by syncthreads), out after ----
            __syncthreads();
            if (tid == 0)
                st_coh32(&flags[wg * FLAG_STRIDE], (unsigned)(it + 1));

            if (layer) {
                __builtin_nontemporal_store(hv,
                    out + ((size_t)t * BATCH + bbase + bl) * DH + jbase + ul);
                if (t == S_LEN - 1)
                    __builtin_nontemporal_store(hv,
                        out + (size_t)S_LEN * BATCH * DH + (size_t)BATCH * DH
                            + (size_t)(bbase + bl) * DH + jbase + ul);
            } else if (t == S_LEN - 1) {
                __builtin_nontemporal_store(hv,
                    out + (size_t)S_LEN * BATCH * DH
                        + (size_t)(bbase + bl) * DH + jbase + ul);
            }
        }
    }
}

extern "C" void kernel_launch(void* const* d_in, const int* in_sizes, int n_in,
                              void* d_out, int out_size, void* d_ws, size_t ws_size,
                              hipStream_t stream) {
    const float* seq    = (const float*)d_in[0];
    const float* h_init = (const float*)d_in[1];
    const float* Wf     = (const float*)d_in[2];
    const float* Bf     = (const float*)d_in[3];
    const float* Wi     = (const float*)d_in[4];
    const float* Bi     = (const float*)d_in[5];
    const float* Wc     = (const float*)d_in[6];
    const float* Bc     = (const float*)d_in[7];
    const float* Wo     = (const float*)d_in[8];
    const float* Bo     = (const float*)d_in[9];
    float* out          = (float*)d_out;
    unsigned short* ws  = (unsigned short*)d_ws;

    hipFuncSetAttribute((const void*)lstm_main,
                        hipFuncAttributeMaxDynamicSharedMemorySize, LDS_BYTES);

    hipLaunchKernelGGL(lstm_init, dim3(128), dim3(THREADS), 0, stream, seq, h_init, ws);

    void* args[] = { (void*)&seq,
                     (void*)&Wf, (void*)&Bf,
                     (void*)&Wi, (void*)&Bi,
                     (void*)&Wc, (void*)&Bc,
                     (void*)&Wo, (void*)&Bo,
                     (void*)&out, (void*)&ws };
    hipLaunchCooperativeKernel((void*)lstm_main, dim3(NWG), dim3(THREADS),
                               args, LDS_BYTES, stream);
}

// Round 15
// 2733.254 us; speedup vs baseline: 3.2445x; 1.2081x over previous
//
#include <hip/hip_runtime.h>
#include <hip/hip_bf16.h>

#define S_LEN   512
#define BATCH   64
#define DH      512
#define KDIM    1024      // 2*DH (concat [h, x])
#define NCOLS   64        // 4 gates * 16 units per WG
#define WGL     128       // WGs per layer
#define NWG     256
#define THREADS 256
#define NSLOT   4         // h rotation depth
#define FLAG_STRIDE 32    // uints: one flag per 128-B line
#define W_LDS_BYTES (NCOLS * KDIM * 2)           // 131072 weights
#define P_LDS_BYTES (16 * 64 * 16)               // 16384 partials
#define LDS_BYTES   (W_LDS_BYTES + P_LDS_BYTES)  // 147456 <= 160K

typedef __attribute__((ext_vector_type(8))) unsigned short u16x8;
typedef __attribute__((ext_vector_type(8))) __bf16         bf16x8;
typedef __attribute__((ext_vector_type(4))) float          f32x4;
typedef __attribute__((ext_vector_type(4))) unsigned       u32x4;

__device__ __forceinline__ unsigned short f2bf(float f) {
    unsigned u = __float_as_uint(f);
    return (unsigned short)((u + 0x7fffu + ((u >> 16) & 1u)) >> 16);   // RNE
}
__device__ __forceinline__ float sigmoid_f(float x) { return 1.f / (1.f + __expf(-x)); }
__device__ __forceinline__ float tanh_f(float x) {
    float e = __expf(2.f * x);
    return 1.f - 2.f / (e + 1.f);
}
__device__ __forceinline__ f32x4 mfma16(bf16x8 a, bf16x8 b, f32x4 c) {
    return __builtin_amdgcn_mfma_f32_16x16x32_bf16(a, b, c, 0, 0, 0);
}
// 32-bit agent-scope relaxed atomics (proven instruction class, compiler-tracked).
__device__ __forceinline__ unsigned ld_coh32(const unsigned* p) {
    return __hip_atomic_load(p, __ATOMIC_RELAXED, __HIP_MEMORY_SCOPE_AGENT);
}
__device__ __forceinline__ void st_coh32(unsigned* p, unsigned v) {
    __hip_atomic_store(p, v, __ATOMIC_RELAXED, __HIP_MEMORY_SCOPE_AGENT);
}

// ws layout (ushort idx unless noted):
//   0      : h0[4][64][512] bf16  (256 KB)  layer0 h rotation
//   131072 : h1[4][64][512] bf16  (256 KB)  layer1 h rotation
//   byte 524288 : flags[256 * 32] uint      per-WG flag, one per 128-B line
//   ushort 278528 : seq_bf16[512][64][512]  (32 MB) pre-converted x input
#define WS_H0    0
#define WS_H1    (NSLOT * BATCH * DH)
#define WS_BAR_B 524288
#define WS_XB    278528

__global__ void lstm_init(const float* __restrict__ seq,
                          const float* __restrict__ h_init,
                          unsigned short* __restrict__ ws) {
    const int gid = blockIdx.x * blockDim.x + threadIdx.x;
    unsigned* flags = (unsigned*)((char*)ws + WS_BAR_B);
    if (gid < NWG) flags[gid * FLAG_STRIDE] = 0;     // re-zeroed every launch
    if (gid < BATCH * DH) {
        ws[WS_H0 + gid] = f2bf(h_init[gid]);                                 // h0 slot0
        ws[WS_H1 + BATCH * DH + gid] = f2bf(h_init[(size_t)BATCH * DH + gid]); // h1 slot1
    }
    // seq fp32 -> bf16 pre-pass (4 elems/thread/iter, grid-stride)
    const size_t total = (size_t)S_LEN * BATCH * DH;           // 16M elems
    const size_t nthr  = (size_t)gridDim.x * blockDim.x;
    for (size_t i = (size_t)gid * 4; i < total; i += nthr * 4) {
        float4 v = *(const float4*)(seq + i);
        unsigned d0 = (unsigned)f2bf(v.x) | ((unsigned)f2bf(v.y) << 16);
        unsigned d1 = (unsigned)f2bf(v.z) | ((unsigned)f2bf(v.w) << 16);
        *(unsigned*)(ws + WS_XB + i)     = d0;
        *(unsigned*)(ws + WS_XB + i + 2) = d1;
    }
}

__global__ __launch_bounds__(THREADS, 1)
void lstm_main(const float* __restrict__ seq,
               const float* __restrict__ Wf, const float* __restrict__ Bf,
               const float* __restrict__ Wi, const float* __restrict__ Bi,
               const float* __restrict__ Wc, const float* __restrict__ Bc,
               const float* __restrict__ Wo, const float* __restrict__ Bo,
               float* __restrict__ out, unsigned short* __restrict__ ws)
{
    extern __shared__ unsigned short wlds[];   // weights [64][1024] bf16 swizzled
    float* plds = (float*)((char*)wlds + W_LDS_BYTES);   // [16 frag][64 lane][4] f32

    const int wg    = blockIdx.x;
    const int layer = wg >> 7;               // 0..1
    const int rid   = wg & (WGL - 1);        // 0..127
    const int us    = rid >> 2;              // unit-slice 0..31
    const int bg    = rid & 3;               // batch-group 0..3
    const int jbase = us * 16;
    const int bbase = bg * 16;
    const int tid   = threadIdx.x;
    const int lane  = tid & 63;
    const int wave  = tid >> 6;

    unsigned short* h0b = ws + WS_H0;
    unsigned short* h1b = ws + WS_H1;
    unsigned* flags = (unsigned*)((char*)ws + WS_BAR_B);

    // ---- stage this WG's weight slice into LDS (bf16, swizzled), once ----
    {
        const size_t woff = (size_t)layer * KDIM * DH;
        const float* Wg[4] = { Wf + woff, Wi + woff, Wc + woff, Wo + woff };
        for (int idx = tid; idx < NCOLS * KDIM; idx += THREADS) {
            int mcol = idx & (NCOLS - 1);          // gate*16 + unit
            int k    = idx >> 6;
            float w  = Wg[mcol >> 4][(size_t)k * DH + jbase + (mcol & 15)];
            unsigned byte = ((unsigned)mcol * 2048u + (unsigned)k * 2u)
                          ^ (((unsigned)mcol & 7u) << 4);
            wlds[byte >> 1] = f2bf(w);
        }
    }

    // MFMA geometry: A=weights (M=16 units), B=acts (N=16 batch).
    // D (m89): col = lane&15 -> batch-local, row = (lane>>4)*4+r -> unit-local.
    const int ln  = lane & 15;
    const int lq  = lane >> 4;
    const int klo = lq * 8;
    const unsigned sw  = ((unsigned)(lane & 7)) << 4;
    const unsigned wbF = (0u * 16 + (unsigned)ln) * 2048u;
    const unsigned wbI = (1u * 16 + (unsigned)ln) * 2048u;
    const unsigned wbC = (2u * 16 + (unsigned)ln) * 2048u;
    const unsigned wbO = (3u * 16 + (unsigned)ln) * 2048u;

    // per-thread output cell: unit ul, batch bl  (256 threads = 16x16 cells)
    const int ul = tid & 15;
    const int bl = tid >> 4;
    const int lidx = (ul >> 2) * 16 + bl;    // source lane in D fragments
    const int ridx = ul & 3;                 // source reg in f32x4
    const float bF = Bf[layer * DH + jbase + ul];
    const float bI = Bi[layer * DH + jbase + ul];
    const float bC = Bc[layer * DH + jbase + ul];
    const float bO = Bo[layer * DH + jbase + ul];

    // ---- per-lane poll setup: exact producers of THIS wave's chunks ----
    // Wave w consumes h-chunks [4w,4w+4) -> producer us in [8w,8w+8), same bg.
    // L0 extra lanes: WAR vs all 32 L1 readers of h0 (need it-2).
    // L1 extra lanes: x = h0 chunks [4w,4w+4) -> 8 L0 producers (need it).
    int fl, noff, mode;                      // mode 0: max(0,it+noff); 1: L1-self; 2: idle
    if (!layer) {
        if (lane < 8)       { fl = ((wave * 8 + lane) << 2) + bg;        noff = 0;  mode = 0; }
        else if (lane < 40) { fl = 128 + ((lane - 8) << 2) + bg;         noff = -2; mode = 0; }
        else                { fl = wg;                                   noff = 0;  mode = 2; }
    } else {
        if (lane < 8)       { fl = 128 + ((wave * 8 + lane) << 2) + bg;  noff = 0;  mode = 1; }
        else if (lane < 16) { fl = ((wave * 8 + (lane - 8)) << 2) + bg;  noff = 0;  mode = 0; }
        else                { fl = wg;                                   noff = 0;  mode = 2; }
    }
    const unsigned* pflag = &flags[fl * FLAG_STRIDE];
    __syncthreads();

    float cs = 0.f;                          // cell state for (ul, bl)

    for (int it = 0; it <= S_LEN; ++it) {
        const bool active = layer ? (it >= 1) : (it < S_LEN);
        const int  t      = layer ? it - 1 : it;
        float hv = 0.f;

        if (active) {
            const int par = it & (NSLOT - 1);

            // ---- L0: prefetch x (seq_bf16, cached, flag-independent) BEFORE poll
            u16x8 xv[4];
            if (!layer) {
                const unsigned short* xb = ws + WS_XB
                    + ((size_t)t * BATCH + bbase + ln) * DH + klo;
                #pragma unroll
                for (int c = 0; c < 4; ++c)
                    xv[c] = *(const u16x8*)(xb + (wave * 4 + c) * 32);
            }

            // ---- per-wave decoupled wait (per-lane heterogeneous needs) ----
            {
                int ni;
                if (mode == 2)      ni = 0;
                else if (mode == 1) ni = (it <= 1) ? 0 : it;
                else                { ni = it + noff; if (ni < 0) ni = 0; }
                const unsigned need = (unsigned)ni;
                unsigned v = ld_coh32(pflag);
                while (!__all((int)(v >= need)))
                    v = ld_coh32(pflag);
            }
            __builtin_amdgcn_sched_barrier(0);

            // ---- coherent loads: 4 h-chunks (16 dwords); L1 also 4 x-chunks ----
            unsigned ah[16], ax[16];
            {
                const unsigned short* hsrc = layer ? h1b : h0b;
                const unsigned* hp = (const unsigned*)
                    (hsrc + (size_t)par * BATCH * DH + (size_t)(bbase + ln) * DH)
                    + wave * 64 + klo / 2;
                #pragma unroll
                for (int c = 0; c < 4; ++c)
                    #pragma unroll
                    for (int d = 0; d < 4; ++d)
                        ah[c * 4 + d] = ld_coh32(hp + c * 16 + d);
            }
            if (layer) {
                const unsigned* xp = (const unsigned*)
                    (h0b + (size_t)par * BATCH * DH + (size_t)(bbase + ln) * DH)
                    + wave * 64 + klo / 2;
                #pragma unroll
                for (int c = 0; c < 4; ++c)
                    #pragma unroll
                    for (int d = 0; d < 4; ++d)
                        ax[c * 4 + d] = ld_coh32(xp + c * 16 + d);
            }

            // ---- 8 chunks x 4 gates MFMA (4 h + 4 x; partials over K=256) ----
            f32x4 eF = {0,0,0,0}, eI = {0,0,0,0}, eC = {0,0,0,0}, eO = {0,0,0,0};
            f32x4 oF = {0,0,0,0}, oI = {0,0,0,0}, oC = {0,0,0,0}, oO = {0,0,0,0};

            #pragma unroll
            for (int c = 0; c < 8; ++c) {
                const int s = (c < 4) ? (wave * 4 + c) : (16 + wave * 4 + (c - 4));
                bf16x8 av;
                if (c < 4) {
                    u32x4 q = { ah[c*4], ah[c*4+1], ah[c*4+2], ah[c*4+3] };
                    av = __builtin_bit_cast(bf16x8, q);
                } else if (!layer) {
                    av = __builtin_bit_cast(bf16x8, xv[c - 4]);
                } else {
                    u32x4 q = { ax[(c-4)*4], ax[(c-4)*4+1], ax[(c-4)*4+2], ax[(c-4)*4+3] };
                    av = __builtin_bit_cast(bf16x8, q);
                }
                const unsigned kb = ((unsigned)s * 64u + (unsigned)klo * 2u) ^ sw;
                bf16x8 wF = __builtin_bit_cast(bf16x8, *(const u16x8*)((const char*)wlds + wbF + kb));
                bf16x8 wI = __builtin_bit_cast(bf16x8, *(const u16x8*)((const char*)wlds + wbI + kb));
                bf16x8 wC = __builtin_bit_cast(bf16x8, *(const u16x8*)((const char*)wlds + wbC + kb));
                bf16x8 wO = __builtin_bit_cast(bf16x8, *(const u16x8*)((const char*)wlds + wbO + kb));
                if (c & 1) {
                    oF = mfma16(wF, av, oF); oI = mfma16(wI, av, oI);
                    oC = mfma16(wC, av, oC); oO = mfma16(wO, av, oO);
                } else {
                    eF = mfma16(wF, av, eF); eI = mfma16(wI, av, eI);
                    eC = mfma16(wC, av, eC); eO = mfma16(wO, av, eO);
                }
            }
            f32x4 pF = eF + oF, pI = eI + oI, pC = eC + oC, pO = eO + oO;

            // ---- cross-wave K-reduction via LDS (join point of all waves) ----
            f32x4* pv = (f32x4*)plds;
            pv[(wave * 4 + 0) * 64 + lane] = pF;
            pv[(wave * 4 + 1) * 64 + lane] = pI;
            pv[(wave * 4 + 2) * 64 + lane] = pC;
            pv[(wave * 4 + 3) * 64 + lane] = pO;
            __syncthreads();

            float sF = 0.f, sI = 0.f, sC = 0.f, sO = 0.f;
            #pragma unroll
            for (int w = 0; w < 4; ++w) {
                sF += plds[((w * 4 + 0) * 64 + lidx) * 4 + ridx];
                sI += plds[((w * 4 + 1) * 64 + lidx) * 4 + ridx];
                sC += plds[((w * 4 + 2) * 64 + lidx) * 4 + ridx];
                sO += plds[((w * 4 + 3) * 64 + lidx) * 4 + ridx];
            }

            const float fg = sigmoid_f(sF + bF);
            const float ig = sigmoid_f(sI + bI);
            const float ct = tanh_f  (sC + bC);
            const float og = sigmoid_f(sO + bO);
            const float cn = fg * cs + ig * ct;
            cs = cn;
            hv = og * tanh_f(cn);

            // ---- h-store: pack unit pairs, write-through (single destination) ----
            const unsigned hb16  = (unsigned)f2bf(hv);
            const unsigned other = (unsigned)__shfl_xor((int)hb16, 1, 64);
            const int npar = (it + 1) & (NSLOT - 1);
            if (!(ul & 1)) {
                unsigned dw = hb16 | (other << 16);
                unsigned short* dst = (layer ? h1b : h0b)
                    + (size_t)npar * BATCH * DH + (size_t)(bbase + bl) * DH + jbase + ul;
                st_coh32((unsigned*)dst, dw);
            }

            // ---- publish EARLY (h-stores drained by syncthreads), out after ----
            __syncthreads();
            if (tid == 0)
                st_coh32(&flags[wg * FLAG_STRIDE], (unsigned)(it + 1));

            if (layer) {
                __builtin_nontemporal_store(hv,
                    out + ((size_t)t * BATCH + bbase + bl) * DH + jbase + ul);
                if (t == S_LEN - 1)
                    __builtin_nontemporal_store(hv,
                        out + (size_t)S_LEN * BATCH * DH + (size_t)BATCH * DH
                            + (size_t)(bbase + bl) * DH + jbase + ul);
            } else if (t == S_LEN - 1) {
                __builtin_nontemporal_store(hv,
                    out + (size_t)S_LEN * BATCH * DH
                        + (size_t)(bbase + bl) * DH + jbase + ul);
            }
        }
    }
}

extern "C" void kernel_launch(void* const* d_in, const int* in_sizes, int n_in,
                              void* d_out, int out_size, void* d_ws, size_t ws_size,
                              hipStream_t stream) {
    const float* seq    = (const float*)d_in[0];
    const float* h_init = (const float*)d_in[1];
    const float* Wf     = (const float*)d_in[2];
    const float* Bf     = (const float*)d_in[3];
    const float* Wi     = (const float*)d_in[4];
    const float* Bi     = (const float*)d_in[5];
    const float* Wc     = (const float*)d_in[6];
    const float* Bc     = (const float*)d_in[7];
    const float* Wo     = (const float*)d_in[8];
    const float* Bo     = (const float*)d_in[9];
    float* out          = (float*)d_out;
    unsigned short* ws  = (unsigned short*)d_ws;

    hipFuncSetAttribute((const void*)lstm_main,
                        hipFuncAttributeMaxDynamicSharedMemorySize, LDS_BYTES);

    hipLaunchKernelGGL(lstm_init, dim3(2048), dim3(THREADS), 0, stream,
                       seq, h_init, ws);

    void* args[] = { (void*)&seq,
                     (void*)&Wf, (void*)&Bf,
                     (void*)&Wi, (void*)&Bi,
                     (void*)&Wc, (void*)&Bc,
                     (void*)&Wo, (void*)&Bo,
                     (void*)&out, (void*)&ws };
    hipLaunchCooperativeKernel((void*)lstm_main, dim3(NWG), dim3(THREADS),
                               args, LDS_BYTES, stream);
}

// Round 16
// 2605.793 us; speedup vs baseline: 3.4032x; 1.0489x over previous
//
#include <hip/hip_runtime.h>
#include <hip/hip_bf16.h>

#define S_LEN   512
#define BATCH   64
#define DH      512
#define KDIM    1024      // 2*DH (concat [h, x])
#define NCOLS   64        // 4 gates * 16 units per WG
#define WGL     128       // WGs per layer
#define NWG     256
#define THREADS 256
#define NSLOT   4         // h rotation depth
#define FLAG_STRIDE 32    // uints: one flag per 128-B line
#define W_LDS_BYTES (NCOLS * KDIM * 2)           // 131072 weights
#define P_LDS_BYTES (16 * 64 * 16)               // 16384 partials
#define LDS_BYTES   (W_LDS_BYTES + P_LDS_BYTES)  // 147456 <= 160K

typedef __attribute__((ext_vector_type(8))) unsigned short u16x8;
typedef __attribute__((ext_vector_type(8))) __bf16         bf16x8;
typedef __attribute__((ext_vector_type(4))) float          f32x4;
typedef __attribute__((ext_vector_type(4))) unsigned       u32x4;

__device__ __forceinline__ unsigned short f2bf(float f) {
    unsigned u = __float_as_uint(f);
    return (unsigned short)((u + 0x7fffu + ((u >> 16) & 1u)) >> 16);   // RNE
}
__device__ __forceinline__ float sigmoid_f(float x) { return 1.f / (1.f + __expf(-x)); }
__device__ __forceinline__ float tanh_f(float x) {
    float e = __expf(2.f * x);
    return 1.f - 2.f / (e + 1.f);
}
__device__ __forceinline__ f32x4 mfma16(bf16x8 a, bf16x8 b, f32x4 c) {
    return __builtin_amdgcn_mfma_f32_16x16x32_bf16(a, b, c, 0, 0, 0);
}
// 32-bit agent-scope relaxed atomics (proven instruction class, compiler-tracked).
__device__ __forceinline__ unsigned ld_coh32(const unsigned* p) {
    return __hip_atomic_load(p, __ATOMIC_RELAXED, __HIP_MEMORY_SCOPE_AGENT);
}
__device__ __forceinline__ void st_coh32(unsigned* p, unsigned v) {
    __hip_atomic_store(p, v, __ATOMIC_RELAXED, __HIP_MEMORY_SCOPE_AGENT);
}

// ws layout (ushort idx unless noted):
//   0      : h0[4][64][512] bf16  (256 KB)  layer0 h rotation
//   131072 : h1[4][64][512] bf16  (256 KB)  layer1 h rotation
//   byte 524288 : flags[256 * 32] uint      per-WG flag, one per 128-B line
//   ushort 278528 : seq_bf16[512][64][512]  (32 MB) pre-converted x input
#define WS_H0    0
#define WS_H1    (NSLOT * BATCH * DH)
#define WS_BAR_B 524288
#define WS_XB    278528

__global__ void lstm_init(const float* __restrict__ seq,
                          const float* __restrict__ h_init,
                          unsigned short* __restrict__ ws) {
    const int gid = blockIdx.x * blockDim.x + threadIdx.x;
    unsigned* flags = (unsigned*)((char*)ws + WS_BAR_B);
    if (gid < NWG) flags[gid * FLAG_STRIDE] = 0;     // re-zeroed every launch
    if (gid < BATCH * DH) {
        ws[WS_H0 + gid] = f2bf(h_init[gid]);                                   // h0 slot0
        ws[WS_H1 + BATCH * DH + gid] = f2bf(h_init[(size_t)BATCH * DH + gid]); // h1 slot1
    }
    // seq fp32 -> bf16 pre-pass (4 elems/thread/iter, grid-stride)
    const size_t total = (size_t)S_LEN * BATCH * DH;           // 16M elems
    const size_t nthr  = (size_t)gridDim.x * blockDim.x;
    for (size_t i = (size_t)gid * 4; i < total; i += nthr * 4) {
        float4 v = *(const float4*)(seq + i);
        unsigned d0 = (unsigned)f2bf(v.x) | ((unsigned)f2bf(v.y) << 16);
        unsigned d1 = (unsigned)f2bf(v.z) | ((unsigned)f2bf(v.w) << 16);
        *(unsigned*)(ws + WS_XB + i)     = d0;
        *(unsigned*)(ws + WS_XB + i + 2) = d1;
    }
}

#define LDWB(off_) __builtin_bit_cast(bf16x8, *(const u16x8*)((const char*)wlds + (off_)))

__global__ __launch_bounds__(THREADS, 1)
void lstm_main(const float* __restrict__ seq,
               const float* __restrict__ Wf, const float* __restrict__ Bf,
               const float* __restrict__ Wi, const float* __restrict__ Bi,
               const float* __restrict__ Wc, const float* __restrict__ Bc,
               const float* __restrict__ Wo, const float* __restrict__ Bo,
               float* __restrict__ out, unsigned short* __restrict__ ws)
{
    extern __shared__ unsigned short wlds[];   // weights [64][1024] bf16 swizzled
    float* plds = (float*)((char*)wlds + W_LDS_BYTES);   // [16 frag][64 lane][4] f32

    const int wg    = blockIdx.x;
    const int layer = wg >> 7;               // 0..1
    const int rid   = wg & (WGL - 1);        // 0..127
    const int us    = rid >> 2;              // unit-slice 0..31
    const int bg    = rid & 3;               // batch-group 0..3
    const int jbase = us * 16;
    const int bbase = bg * 16;
    const int tid   = threadIdx.x;
    const int lane  = tid & 63;
    const int wave  = tid >> 6;

    unsigned short* h0b = ws + WS_H0;
    unsigned short* h1b = ws + WS_H1;
    unsigned* flags = (unsigned*)((char*)ws + WS_BAR_B);

    // ---- stage this WG's weight slice into LDS (bf16, swizzled), once ----
    {
        const size_t woff = (size_t)layer * KDIM * DH;
        const float* Wg[4] = { Wf + woff, Wi + woff, Wc + woff, Wo + woff };
        for (int idx = tid; idx < NCOLS * KDIM; idx += THREADS) {
            int mcol = idx & (NCOLS - 1);          // gate*16 + unit
            int k    = idx >> 6;
            float w  = Wg[mcol >> 4][(size_t)k * DH + jbase + (mcol & 15)];
            unsigned byte = ((unsigned)mcol * 2048u + (unsigned)k * 2u)
                          ^ (((unsigned)mcol & 7u) << 4);
            wlds[byte >> 1] = f2bf(w);
        }
    }

    // MFMA geometry: A=weights (M=16 units), B=acts (N=16 batch).
    // D (m89): col = lane&15 -> batch-local, row = (lane>>4)*4+r -> unit-local.
    const int ln  = lane & 15;
    const int lq  = lane >> 4;
    const int klo = lq * 8;
    const unsigned sw  = ((unsigned)(lane & 7)) << 4;
    const unsigned wbF = (0u * 16 + (unsigned)ln) * 2048u;
    const unsigned wbI = (1u * 16 + (unsigned)ln) * 2048u;
    const unsigned wbC = (2u * 16 + (unsigned)ln) * 2048u;
    const unsigned wbO = (3u * 16 + (unsigned)ln) * 2048u;

    // per-thread output cell: unit ul, batch bl  (256 threads = 16x16 cells)
    const int ul = tid & 15;
    const int bl = tid >> 4;
    const int lidx = (ul >> 2) * 16 + bl;    // source lane in D fragments
    const int ridx = ul & 3;                 // source reg in f32x4
    const float bF = Bf[layer * DH + jbase + ul];
    const float bI = Bi[layer * DH + jbase + ul];
    const float bC = Bc[layer * DH + jbase + ul];
    const float bO = Bo[layer * DH + jbase + ul];

    // ---- poll pointers ----
    // L0 (single poll B): lanes<8 self producers (need it); lanes 8..39 WAR vs
    //   32 L1 same-bg readers of h0 (need it-2); else idle.
    // L1: phase A = x-dep on 8 L0 producers (need it, ~1 period slack);
    //     phase B = h1 self-dep on 8 L1 producers (need it, tight).
    int flA = wg, flB = wg;
    if (!layer) {
        if (lane < 8)       flB = ((wave * 8 + lane) << 2) + bg;
        else if (lane < 40) flB = 128 + ((lane - 8) << 2) + bg;
    } else {
        if (lane >= 8 && lane < 16) flA = ((wave * 8 + (lane - 8)) << 2) + bg;
        if (lane < 8)               flB = 128 + ((wave * 8 + lane) << 2) + bg;
    }
    const unsigned* pfA = &flags[flA * FLAG_STRIDE];
    const unsigned* pfB = &flags[flB * FLAG_STRIDE];
    __syncthreads();

    float cs = 0.f;                          // cell state for (ul, bl)

    for (int it = 0; it <= S_LEN; ++it) {
        const bool active = layer ? (it >= 1) : (it < S_LEN);
        const int  t      = layer ? it - 1 : it;
        float hv = 0.f;

        if (active) {
            const int par = it & (NSLOT - 1);
            f32x4 eF = {0,0,0,0}, eI = {0,0,0,0}, eC = {0,0,0,0}, eO = {0,0,0,0};
            f32x4 oF = {0,0,0,0}, oI = {0,0,0,0}, oC = {0,0,0,0}, oO = {0,0,0,0};

            // ---- h-weight fragments preloaded (off the gated path) ----
            bf16x8 whF[4], whI[4], whC[4], whO[4];
            #pragma unroll
            for (int c = 0; c < 4; ++c) {
                const unsigned kb = ((unsigned)(wave * 4 + c) * 64u
                                     + (unsigned)klo * 2u) ^ sw;
                whF[c] = LDWB(wbF + kb); whI[c] = LDWB(wbI + kb);
                whC[c] = LDWB(wbC + kb); whO[c] = LDWB(wbO + kb);
            }

            unsigned ah[16];

            if (!layer) {
                // ---- x-half entirely pre-poll (seq_bf16, cached, flag-free) ----
                const unsigned short* xb = ws + WS_XB
                    + ((size_t)t * BATCH + bbase + ln) * DH + klo;
                #pragma unroll
                for (int c = 0; c < 4; ++c) {
                    u16x8 xv = *(const u16x8*)(xb + (16 + wave * 4 + c - 16) * 32
                                               + wave * 0 + (c) * 0);
                    // x-chunk s = 16 + wave*4 + c  -> seq element offset (s-16)*32
                    xv = *(const u16x8*)(xb + (wave * 4 + c) * 32);
                    bf16x8 av = __builtin_bit_cast(bf16x8, xv);
                    const unsigned kb = ((unsigned)(16 + wave * 4 + c) * 64u
                                         + (unsigned)klo * 2u) ^ sw;
                    bf16x8 wFx = LDWB(wbF + kb), wIx = LDWB(wbI + kb);
                    bf16x8 wCx = LDWB(wbC + kb), wOx = LDWB(wbO + kb);
                    if (c & 1) {
                        oF = mfma16(wFx, av, oF); oI = mfma16(wIx, av, oI);
                        oC = mfma16(wCx, av, oC); oO = mfma16(wOx, av, oO);
                    } else {
                        eF = mfma16(wFx, av, eF); eI = mfma16(wIx, av, eI);
                        eC = mfma16(wCx, av, eC); eO = mfma16(wOx, av, eO);
                    }
                }
                // ---- tight poll (self h-dep + WAR) ----
                {
                    int ni = (lane < 8) ? it : ((lane < 40) ? it - 2 : 0);
                    if (ni < 0) ni = 0;
                    const unsigned need = (unsigned)ni;
                    unsigned v = ld_coh32(pfB);
                    while (!__all((int)(v >= need)))
                        v = ld_coh32(pfB);
                }
                __builtin_amdgcn_sched_barrier(0);
                // ---- gated region: 16 coherent dwords + 4 MFMAs ----
                const unsigned* hp = (const unsigned*)
                    (h0b + (size_t)par * BATCH * DH + (size_t)(bbase + ln) * DH)
                    + wave * 64 + klo / 2;
                #pragma unroll
                for (int c = 0; c < 4; ++c)
                    #pragma unroll
                    for (int d = 0; d < 4; ++d)
                        ah[c * 4 + d] = ld_coh32(hp + c * 16 + d);
            } else {
                // ---- phase A: x-dep (slack ~1 period; instant steady-state) ----
                {
                    const unsigned need = (lane >= 8 && lane < 16) ? (unsigned)it : 0u;
                    unsigned v = ld_coh32(pfA);
                    while (!__all((int)(v >= need)))
                        v = ld_coh32(pfA);
                }
                __builtin_amdgcn_sched_barrier(0);
                // issue x loads (h0) -> flight overlaps phase B poll
                unsigned ax[16];
                const unsigned* xp = (const unsigned*)
                    (h0b + (size_t)par * BATCH * DH + (size_t)(bbase + ln) * DH)
                    + wave * 64 + klo / 2;
                #pragma unroll
                for (int c = 0; c < 4; ++c)
                    #pragma unroll
                    for (int d = 0; d < 4; ++d)
                        ax[c * 4 + d] = ld_coh32(xp + c * 16 + d);
                // ---- phase B: tight h1 self-dep ----
                {
                    const unsigned need = (lane < 8)
                        ? (unsigned)((it <= 1) ? 0 : it) : 0u;
                    unsigned v = ld_coh32(pfB);
                    while (!__all((int)(v >= need)))
                        v = ld_coh32(pfB);
                }
                __builtin_amdgcn_sched_barrier(0);
                // issue h loads -> flight overlaps x-MFMAs
                const unsigned* hp = (const unsigned*)
                    (h1b + (size_t)par * BATCH * DH + (size_t)(bbase + ln) * DH)
                    + wave * 64 + klo / 2;
                #pragma unroll
                for (int c = 0; c < 4; ++c)
                    #pragma unroll
                    for (int d = 0; d < 4; ++d)
                        ah[c * 4 + d] = ld_coh32(hp + c * 16 + d);
                // x-MFMAs (consume ax; h loads in flight)
                #pragma unroll
                for (int c = 0; c < 4; ++c) {
                    u32x4 q = { ax[c*4], ax[c*4+1], ax[c*4+2], ax[c*4+3] };
                    bf16x8 av = __builtin_bit_cast(bf16x8, q);
                    const unsigned kb = ((unsigned)(16 + wave * 4 + c) * 64u
                                         + (unsigned)klo * 2u) ^ sw;
                    bf16x8 wFx = LDWB(wbF + kb), wIx = LDWB(wbI + kb);
                    bf16x8 wCx = LDWB(wbC + kb), wOx = LDWB(wbO + kb);
                    if (c & 1) {
                        oF = mfma16(wFx, av, oF); oI = mfma16(wIx, av, oI);
                        oC = mfma16(wCx, av, oC); oO = mfma16(wOx, av, oO);
                    } else {
                        eF = mfma16(wFx, av, eF); eI = mfma16(wIx, av, eI);
                        eC = mfma16(wCx, av, eC); eO = mfma16(wOx, av, eO);
                    }
                }
            }

            // ---- h-MFMAs with preloaded weight fragments ----
            #pragma unroll
            for (int c = 0; c < 4; ++c) {
                u32x4 q = { ah[c*4], ah[c*4+1], ah[c*4+2], ah[c*4+3] };
                bf16x8 av = __builtin_bit_cast(bf16x8, q);
                if (c & 1) {
                    oF = mfma16(whF[c], av, oF); oI = mfma16(whI[c], av, oI);
                    oC = mfma16(whC[c], av, oC); oO = mfma16(whO[c], av, oO);
                } else {
                    eF = mfma16(whF[c], av, eF); eI = mfma16(whI[c], av, eI);
                    eC = mfma16(whC[c], av, eC); eO = mfma16(whO[c], av, eO);
                }
            }
            f32x4 pF = eF + oF, pI = eI + oI, pC = eC + oC, pO = eO + oO;

            // ---- cross-wave K-reduction via LDS (join point of all waves) ----
            f32x4* pv = (f32x4*)plds;
            pv[(wave * 4 + 0) * 64 + lane] = pF;
            pv[(wave * 4 + 1) * 64 + lane] = pI;
            pv[(wave * 4 + 2) * 64 + lane] = pC;
            pv[(wave * 4 + 3) * 64 + lane] = pO;
            __syncthreads();

            float sF = 0.f, sI = 0.f, sC = 0.f, sO = 0.f;
            #pragma unroll
            for (int w = 0; w < 4; ++w) {
                sF += plds[((w * 4 + 0) * 64 + lidx) * 4 + ridx];
                sI += plds[((w * 4 + 1) * 64 + lidx) * 4 + ridx];
                sC += plds[((w * 4 + 2) * 64 + lidx) * 4 + ridx];
                sO += plds[((w * 4 + 3) * 64 + lidx) * 4 + ridx];
            }

            const float fg = sigmoid_f(sF + bF);
            const float ig = sigmoid_f(sI + bI);
            const float ct = tanh_f  (sC + bC);
            const float og = sigmoid_f(sO + bO);
            const float cn = fg * cs + ig * ct;
            cs = cn;
            hv = og * tanh_f(cn);

            // ---- h-store: pack unit pairs, write-through (single destination) ----
            const unsigned hb16  = (unsigned)f2bf(hv);
            const unsigned other = (unsigned)__shfl_xor((int)hb16, 1, 64);
            const int npar = (it + 1) & (NSLOT - 1);
            if (!(ul & 1)) {
                unsigned dw = hb16 | (other << 16);
                unsigned short* dst = (layer ? h1b : h0b)
                    + (size_t)npar * BATCH * DH + (size_t)(bbase + bl) * DH + jbase + ul;
                st_coh32((unsigned*)dst, dw);
            }

            // ---- publish EARLY (h-stores drained by syncthreads), out after ----
            __syncthreads();
            if (tid == 0)
                st_coh32(&flags[wg * FLAG_STRIDE], (unsigned)(it + 1));

            if (layer) {
                __builtin_nontemporal_store(hv,
                    out + ((size_t)t * BATCH + bbase + bl) * DH + jbase + ul);
                if (t == S_LEN - 1)
                    __builtin_nontemporal_store(hv,
                        out + (size_t)S_LEN * BATCH * DH + (size_t)BATCH * DH
                            + (size_t)(bbase + bl) * DH + jbase + ul);
            } else if (t == S_LEN - 1) {
                __builtin_nontemporal_store(hv,
                    out + (size_t)S_LEN * BATCH * DH
                        + (size_t)(bbase + bl) * DH + jbase + ul);
            }
        }
    }
}

extern "C" void kernel_launch(void* const* d_in, const int* in_sizes, int n_in,
                              void* d_out, int out_size, void* d_ws, size_t ws_size,
                              hipStream_t stream) {
    const float* seq    = (const float*)d_in[0];
    const float* h_init = (const float*)d_in[1];
    const float* Wf     = (const float*)d_in[2];
    const float* Bf     = (const float*)d_in[3];
    const float* Wi     = (const float*)d_in[4];
    const float* Bi     = (const float*)d_in[5];
    const float* Wc     = (const float*)d_in[6];
    const float* Bc     = (const float*)d_in[7];
    const float* Wo     = (const float*)d_in[8];
    const float* Bo     = (const float*)d_in[9];
    float* out          = (float*)d_out;
    unsigned short* ws  = (unsigned short*)d_ws;

    hipFuncSetAttribute((const void*)lstm_main,
                        hipFuncAttributeMaxDynamicSharedMemorySize, LDS_BYTES);

    hipLaunchKernelGGL(lstm_init, dim3(2048), dim3(THREADS), 0, stream,
                       seq, h_init, ws);

    void* args[] = { (void*)&seq,
                     (void*)&Wf, (void*)&Bf,
                     (void*)&Wi, (void*)&Bi,
                     (void*)&Wc, (void*)&Bc,
                     (void*)&Wo, (void*)&Bo,
                     (void*)&out, (void*)&ws };
    hipLaunchCooperativeKernel((void*)lstm_main, dim3(NWG), dim3(THREADS),
                               args, LDS_BYTES, stream);
}